// Round 3
// baseline (1783.586 us; speedup 1.0000x reference)
//
#include <hip/hip_runtime.h>
#include <hip/hip_bf16.h>

typedef __hip_bfloat16 bf16;

__device__ __forceinline__ float b2f(bf16 x){ return __bfloat162float(x); }
__device__ __forceinline__ bf16  f2b(float x){ return __float2bfloat16(x); }
__device__ __forceinline__ float ldA(const float* p){ return *p; }
__device__ __forceinline__ float ldA(const bf16* p){ return b2f(*p); }

#define BTOK 2048
#define CC 1024
#define AA 1024
#define IDIM 3584
#define NEXP 8
#define CHUNK 64
#define NCHUNK 16   // 1024 / CHUNK

// ---------------- MFMA types / helpers ----------------
typedef __attribute__((ext_vector_type(8))) short   s8v;   // 8 bf16 bit-patterns (staging)
typedef __attribute__((ext_vector_type(8))) __bf16  b8v;   // MFMA A/B fragment
typedef __attribute__((ext_vector_type(4))) float   f4v;   // MFMA C/D fragment

__device__ __forceinline__ unsigned short f2bf_bits(float f){   // RNE, matches __float2bfloat16
  unsigned u = __builtin_bit_cast(unsigned, f);
  u += 0x7fffu + ((u >> 16) & 1u);
  return (unsigned short)(u >> 16);
}

// ---------------- reductions ----------------
__device__ __forceinline__ float block_sum256(float v, float* red){
  #pragma unroll
  for (int o = 32; o > 0; o >>= 1) v += __shfl_down(v, o, 64);
  int lane = threadIdx.x & 63, wid = threadIdx.x >> 6;
  if (lane == 0) red[wid] = v;
  __syncthreads();
  float s = red[0] + red[1] + red[2] + red[3];
  __syncthreads();
  return s;
}

// ---------------- fused pre_ln + ln1 (f32 in, f32 out) ----------------
__global__ __launch_bounds__(256) void k_ln_pre(
    const float* __restrict__ hidden,
    const float* __restrict__ g0, const float* __restrict__ b0,
    const float* __restrict__ g1, const float* __restrict__ b1,
    float* __restrict__ xout, float* __restrict__ hout){
  __shared__ float red[8];
  int t = blockIdx.x, tid = threadIdx.x;
  const float* src = hidden + (size_t)t * CC;
  float v[4];
  #pragma unroll
  for (int i = 0; i < 4; ++i) v[i] = src[tid + 256*i];
  float mean = block_sum256(v[0]+v[1]+v[2]+v[3], red) * (1.f/CC);
  float vs = 0.f;
  #pragma unroll
  for (int i = 0; i < 4; ++i){ float d = v[i]-mean; vs += d*d; }
  float var = block_sum256(vs, red) * (1.f/CC);
  float inv = rsqrtf(var + 1e-5f);
  float xv[4];
  #pragma unroll
  for (int i = 0; i < 4; ++i){
    int c = tid + 256*i;
    xv[i] = (v[i]-mean)*inv*g0[c] + b0[c];
    xout[(size_t)t*CC + c] = xv[i];
  }
  float mean2 = block_sum256(xv[0]+xv[1]+xv[2]+xv[3], red) * (1.f/CC);
  vs = 0.f;
  #pragma unroll
  for (int i = 0; i < 4; ++i){ float d = xv[i]-mean2; vs += d*d; }
  float var2 = block_sum256(vs, red) * (1.f/CC);
  float inv2 = rsqrtf(var2 + 1e-5f);
  #pragma unroll
  for (int i = 0; i < 4; ++i){
    int c = tid + 256*i;
    hout[(size_t)t*CC + c] = (xv[i]-mean2)*inv2*g1[c] + b1[c];
  }
}

// ---------------- token-shift + maa mix -> z_{w,k,v,r,g} (bf16 scratch) ----------------
__global__ __launch_bounds__(256) void k_mix_att(
    const float* __restrict__ h,
    const float* __restrict__ maa_x, const float* __restrict__ w1, const float* __restrict__ w2,
    const float* __restrict__ maa_w, const float* __restrict__ maa_k, const float* __restrict__ maa_v,
    const float* __restrict__ maa_r, const float* __restrict__ maa_g,
    bf16* __restrict__ zw, bf16* __restrict__ zk, bf16* __restrict__ zv,
    bf16* __restrict__ zr, bf16* __restrict__ zg){
  int t = blockIdx.x, tid = threadIdx.x;
  int tb = t & 1023;  // position within batch (T=1024)
  __shared__ float hs[CC], xxs[CC], xxxs[CC], t160[160];
  #pragma unroll
  for (int i = 0; i < 4; ++i){
    int c = tid + 256*i;
    float hv = h[(size_t)t*CC + c];
    float pv = tb ? h[(size_t)(t-1)*CC + c] : 0.f;  // time_shift: zero-pad first token
    float xx = pv - hv;
    hs[c] = hv; xxs[c] = xx;
    xxxs[c] = hv + xx * maa_x[c];
  }
  __syncthreads();
  if (tid < 160){
    float acc = 0.f;
    for (int c = 0; c < CC; ++c) acc = fmaf(xxxs[c], w1[c*160 + tid], acc);
    t160[tid] = tanhf(acc);
  }
  __syncthreads();
  const float* maas[5] = {maa_w, maa_k, maa_v, maa_r, maa_g};
  bf16* zs[5] = {zw, zk, zv, zr, zg};
  #pragma unroll
  for (int f = 0; f < 5; ++f){
    #pragma unroll
    for (int i = 0; i < 4; ++i){
      int c = tid + 256*i;
      float acc = 0.f;
      #pragma unroll
      for (int d = 0; d < 32; ++d)
        acc = fmaf(t160[f*32 + d], w2[(size_t)(f*32 + d)*CC + c], acc);
      float z = hs[c] + xxs[c] * (maas[f][c] + acc);
      zs[f][(size_t)t*CC + c] = f2b(z);
    }
  }
}

// ---------------- small VALU GEMM (td path only): O = A[M,K] @ W[N,K]^T ----------------
#define BM 64
#define BN 64
#define BK 16
template <typename TA>
__global__ __launch_bounds__(256) void k_gemm(
    const TA* __restrict__ A, const float* __restrict__ W,
    float* __restrict__ Of32, bf16* __restrict__ Obf,
    int M, int N, int K, int epi){
  __shared__ float As[BK][BM+1];
  __shared__ float Bs[BK][BN+1];
  int bn = blockIdx.x * BN, bm = blockIdx.y * BM;
  int tid = threadIdx.x;
  int tx = tid & 15, ty = tid >> 4;
  int lr = tid >> 2;          // 0..63
  int lk = (tid & 3) * 4;     // 0,4,8,12
  const TA*    Ap = A + (size_t)(bm + lr)*K + lk;
  const float* Wp = W + (size_t)(bn + lr)*K + lk;
  float acc[4][4] = {};
  for (int k0 = 0; k0 < K; k0 += BK){
    #pragma unroll
    for (int j = 0; j < 4; ++j){
      As[lk+j][lr] = ldA(Ap + k0 + j);
      Bs[lk+j][lr] = Wp[k0 + j];
    }
    __syncthreads();
    #pragma unroll
    for (int kk = 0; kk < BK; ++kk){
      float av[4], bv[4];
      #pragma unroll
      for (int i = 0; i < 4; ++i) av[i] = As[kk][ty*4 + i];
      #pragma unroll
      for (int j = 0; j < 4; ++j) bv[j] = Bs[kk][tx*4 + j];
      #pragma unroll
      for (int i = 0; i < 4; ++i)
        #pragma unroll
        for (int j = 0; j < 4; ++j) acc[i][j] = fmaf(av[i], bv[j], acc[i][j]);
    }
    __syncthreads();
  }
  #pragma unroll
  for (int i = 0; i < 4; ++i){
    int row = bm + ty*4 + i;
    #pragma unroll
    for (int j = 0; j < 4; ++j){
      int col = bn + tx*4 + j;
      size_t oi = (size_t)row*N + col;
      float v = acc[i][j];
      if (epi == 0){
        Of32[oi] = v;
      } else {
        v = v > 0.f ? v : 0.f;
        Obf[oi] = f2b(v*v);
      }
    }
  }
}

// ================= MFMA GEMM: O[M,N] = A[M,K] @ W[N,K]^T (bf16 MFMA, f32 acc) =================
// Tile 64x64x32; 256 threads = 4 waves in 2x2; wave computes 32x32 (2x2 frags of 16x16x32).
// Software pipeline: global loads for step t+1 issue after barrier2 of step t; raw f32 W bits
// held in regs, converted to bf16 at LDS-write time -> load latency hides under ds_read+MFMA.
// LDS rows are 64B: staging writes are 16B/lane linear; frag reads cover all 32 banks evenly.
// A-frag: row=lane&15, k=(lane>>4)*8+j ; B-frag: col=lane&15 ; C/D: col=lane&15,
// row=(lane>>4)*4+reg  [measured m89/m91].
#define GM 64
#define GN 64
#define GK 32

template<int AF32, int EPI>   // AF32: A is f32 (cvt on stage) else bf16 bits. EPI: 0 f32 store, 1 relu^2 bf16
__global__ __launch_bounds__(256) void k_mgemm(
    const void* __restrict__ Av, const float* __restrict__ W,
    float* __restrict__ Of32, unsigned short* __restrict__ Obf,
    int N, int K){
  __shared__ unsigned short As[GM*GK];
  __shared__ unsigned short Bs[GN*GK];
  const int tid = threadIdx.x;
  const int bm = blockIdx.y*GM, bn = blockIdx.x*GN;
  const int w = tid >> 6, l = tid & 63;
  const int mr = (w >> 1)*32, nc = (w & 1)*32;
  const int sr = tid >> 2, sc = tid & 3;      // staging: row sr (0..63), 8-elem chunk sc
  const unsigned short* Arow_b = (const unsigned short*)Av + (size_t)(bm+sr)*K + sc*8;
  const float*          Arow_f = (const float*)Av          + (size_t)(bm+sr)*K + sc*8;
  const float*          Wrow   = W + (size_t)(bn+sr)*K + sc*8;

  f4v acc[2][2];
  #pragma unroll
  for (int i = 0; i < 2; ++i)
    #pragma unroll
    for (int j = 0; j < 2; ++j){ f4v z = {0.f,0.f,0.f,0.f}; acc[i][j] = z; }

  s8v a_bf; f4v af0, af1, wf0, wf1;
  if (AF32){ af0 = *(const f4v*)(Arow_f); af1 = *(const f4v*)(Arow_f + 4); }
  else       a_bf = *(const s8v*)(Arow_b);
  wf0 = *(const f4v*)(Wrow); wf1 = *(const f4v*)(Wrow + 4);

  const int nk = K/GK;
  for (int kt = 0; kt < nk; ++kt){
    s8v aw, bw;
    if (AF32){
      #pragma unroll
      for (int j = 0; j < 4; ++j){ aw[j] = (short)f2bf_bits(af0[j]); aw[4+j] = (short)f2bf_bits(af1[j]); }
    } else aw = a_bf;
    #pragma unroll
    for (int j = 0; j < 4; ++j){ bw[j] = (short)f2bf_bits(wf0[j]); bw[4+j] = (short)f2bf_bits(wf1[j]); }
    __syncthreads();                           // prior step's frag reads done
    *(s8v*)&As[sr*GK + sc*8] = aw;
    *(s8v*)&Bs[sr*GK + sc*8] = bw;
    __syncthreads();
    if (kt + 1 < nk){                          // prefetch next step into regs
      int k0 = (kt+1)*GK;
      if (AF32){ af0 = *(const f4v*)(Arow_f + k0); af1 = *(const f4v*)(Arow_f + k0 + 4); }
      else       a_bf = *(const s8v*)(Arow_b + k0);
      wf0 = *(const f4v*)(Wrow + k0); wf1 = *(const f4v*)(Wrow + k0 + 4);
    }
    b8v afr[2], bfr[2];
    #pragma unroll
    for (int f = 0; f < 2; ++f){
      afr[f] = *(const b8v*)&As[(mr + f*16 + (l&15))*GK + (l>>4)*8];
      bfr[f] = *(const b8v*)&Bs[(nc + f*16 + (l&15))*GK + (l>>4)*8];
    }
    #pragma unroll
    for (int fr = 0; fr < 2; ++fr)
      #pragma unroll
      for (int fc = 0; fc < 2; ++fc)
        acc[fr][fc] = __builtin_amdgcn_mfma_f32_16x16x32_bf16(afr[fr], bfr[fc], acc[fr][fc], 0, 0, 0);
  }
  const int rb = bm + mr + ((l >> 4) << 2);
  const int cb = bn + nc + (l & 15);
  #pragma unroll
  for (int fr = 0; fr < 2; ++fr)
    #pragma unroll
    for (int fc = 0; fc < 2; ++fc)
      #pragma unroll
      for (int j = 0; j < 4; ++j){
        size_t oi = (size_t)(rb + fr*16 + j)*N + (cb + fc*16);
        float v = acc[fr][fc][j];
        if (EPI == 0) Of32[oi] = v;
        else { v = v > 0.f ? v : 0.f; Obf[oi] = f2bf_bits(v*v); }
      }
}

// ---------------- MoE MFMA GEMM (gather/scatter), 64x64 tile + prefetch ----------------
// grid = (row_tiles_max, N/GN, NEXP): x = row-tile (dead blocks return fast)
// MODE 0: A rows gathered via rowmap (zfk), out rows compact, epi relu^2 -> bf16
// MODE 1: A rows compact (hk2), out rows scattered via rowmap, Of32 += acc
template<int MODE>
__global__ __launch_bounds__(256) void k_mgemm_moe(
    const unsigned short* __restrict__ A, const float* __restrict__ Wbase, size_t wstride,
    float* __restrict__ Of32, unsigned short* __restrict__ Obf, int N, int K,
    const int* __restrict__ rowmap, const int* __restrict__ counts,
    const int* __restrict__ offsets){
  const int e = blockIdx.z;
  const int cnt = counts[e];
  const int mbase = blockIdx.x*GM;
  if (mbase >= cnt) return;
  const int obase = offsets[e];
  const float* W = Wbase + (size_t)e*wstride;
  __shared__ unsigned short As[GM*GK];
  __shared__ unsigned short Bs[GN*GK];
  const int tid = threadIdx.x;
  const int bn = blockIdx.y*GN;
  const int w = tid >> 6, l = tid & 63;
  const int mr = (w >> 1)*32, nc = (w & 1)*32;
  const int sr = tid >> 2, sc = tid & 3;

  int lr = mbase + sr;
  lr = lr < cnt ? lr : cnt - 1;                // clamp: garbage rows masked at epilogue
  const int arow = (MODE == 0) ? rowmap[obase + lr] : (obase + lr);
  const unsigned short* Arow = A + (size_t)arow*K + sc*8;
  const float*          Wrow = W + (size_t)(bn+sr)*K + sc*8;

  f4v acc[2][2];
  #pragma unroll
  for (int i = 0; i < 2; ++i)
    #pragma unroll
    for (int j = 0; j < 2; ++j){ f4v z = {0.f,0.f,0.f,0.f}; acc[i][j] = z; }

  s8v a_bf = *(const s8v*)(Arow);
  f4v wf0 = *(const f4v*)(Wrow), wf1 = *(const f4v*)(Wrow + 4);

  const int nk = K/GK;
  for (int kt = 0; kt < nk; ++kt){
    s8v bw;
    #pragma unroll
    for (int j = 0; j < 4; ++j){ bw[j] = (short)f2bf_bits(wf0[j]); bw[4+j] = (short)f2bf_bits(wf1[j]); }
    s8v aw = a_bf;
    __syncthreads();
    *(s8v*)&As[sr*GK + sc*8] = aw;
    *(s8v*)&Bs[sr*GK + sc*8] = bw;
    __syncthreads();
    if (kt + 1 < nk){
      int k0 = (kt+1)*GK;
      a_bf = *(const s8v*)(Arow + k0);
      wf0 = *(const f4v*)(Wrow + k0); wf1 = *(const f4v*)(Wrow + k0 + 4);
    }
    b8v afr[2], bfr[2];
    #pragma unroll
    for (int f = 0; f < 2; ++f){
      afr[f] = *(const b8v*)&As[(mr + f*16 + (l&15))*GK + (l>>4)*8];
      bfr[f] = *(const b8v*)&Bs[(nc + f*16 + (l&15))*GK + (l>>4)*8];
    }
    #pragma unroll
    for (int fr = 0; fr < 2; ++fr)
      #pragma unroll
      for (int fc = 0; fc < 2; ++fc)
        acc[fr][fc] = __builtin_amdgcn_mfma_f32_16x16x32_bf16(afr[fr], bfr[fc], acc[fr][fc], 0, 0, 0);
  }
  const int rb = mbase + mr + ((l >> 4) << 2);
  const int cb = bn + nc + (l & 15);
  #pragma unroll
  for (int fr = 0; fr < 2; ++fr)
    #pragma unroll
    for (int fc = 0; fc < 2; ++fc)
      #pragma unroll
      for (int j = 0; j < 4; ++j){
        int lrow = rb + fr*16 + j;
        if (lrow >= cnt) continue;
        int col = cb + fc*16;
        float v = acc[fr][fc][j];
        if (MODE == 0){
          size_t oi = (size_t)(obase + lrow)*N + col;
          v = v > 0.f ? v : 0.f;
          Obf[oi] = f2bf_bits(v*v);
        } else {
          int orow = rowmap[obase + lrow];
          Of32[(size_t)orow*N + col] += v;     // unique (row,col) writer across experts
        }
      }
}

// ================= chunk-parallel WKV =================
__global__ void k_wprep(const float* __restrict__ td, const float* __restrict__ bias,
                        float* __restrict__ wbuf, int n){
  int i = blockIdx.x*256 + threadIdx.x;
  if (i >= n) return;
  wbuf[i] = expf(-expf(td[i] + bias[i & (AA-1)]));
}

// pass 1: per (stream=b*16+h, chunk): B_c[n][m], A_c[n]
__global__ __launch_bounds__(64) void k_wkv_chunk(
    const float* __restrict__ kb, const float* __restrict__ vb,
    const float* __restrict__ wb, float* __restrict__ Bc, float* __restrict__ Ac){
  int blk = blockIdx.x;
  int stream = blk >> 4, c = blk & (NCHUNK-1);
  int b = stream >> 4, hh = stream & 15;
  int lane = threadIdx.x;          // m column (and n for the A-product)
  __shared__ float ks[64], ws[64];
  float s[64];
  #pragma unroll
  for (int n = 0; n < 64; ++n) s[n] = 0.f;
  float prod = 1.f;
  int t0 = c * CHUNK;
  for (int tt = 0; tt < CHUNK; ++tt){
    size_t idx = ((size_t)(b*1024 + t0 + tt))*AA + hh*64 + lane;
    float kt = kb[idx], vt = vb[idx], wt = wb[idx];
    __syncthreads();
    ks[lane] = kt; ws[lane] = wt;
    __syncthreads();
    prod *= wt;                     // lane acts as n here
    #pragma unroll
    for (int n = 0; n < 64; ++n)
      s[n] = fmaf(ws[n], s[n], ks[n]*vt);
  }
  float* Bp = Bc + ((size_t)stream*NCHUNK + c)*4096;
  #pragma unroll
  for (int n = 0; n < 64; ++n) Bp[n*64 + lane] = s[n];
  Ac[((size_t)stream*NCHUNK + c)*64 + lane] = prod;
}

// pass 2: sequential over chunks; overwrite Bc slots with chunk-INITIAL states
__global__ __launch_bounds__(64) void k_wkv_combine(
    float* __restrict__ Bc, const float* __restrict__ Ac){
  int stream = blockIdx.x;
  int lane = threadIdx.x;          // m
  __shared__ float as[64];
  float S[64];
  #pragma unroll
  for (int n = 0; n < 64; ++n) S[n] = 0.f;
  for (int c = 0; c < NCHUNK; ++c){
    __syncthreads();
    as[lane] = Ac[((size_t)stream*NCHUNK + c)*64 + lane];
    __syncthreads();
    float* Bp = Bc + ((size_t)stream*NCHUNK + c)*4096;
    #pragma unroll
    for (int n = 0; n < 64; ++n){
      float bcv = Bp[n*64 + lane];
      Bp[n*64 + lane] = S[n];                 // store chunk-initial state
      S[n] = fmaf(as[n], S[n], bcv);
    }
  }
}

// pass 3: replay each chunk from its initial state, emit outputs
__global__ __launch_bounds__(64) void k_wkv_out(
    const float* __restrict__ rb, const float* __restrict__ kb,
    const float* __restrict__ vb, const float* __restrict__ wb,
    const float* __restrict__ u, const float* __restrict__ Sc,
    float* __restrict__ ob){
  int blk = blockIdx.x;
  int stream = blk >> 4, c = blk & (NCHUNK-1);
  int b = stream >> 4, hh = stream & 15;
  int lane = threadIdx.x;          // m
  __shared__ float rs[64], ks[64], ws[64], us[64];
  us[lane] = u[hh*64 + lane];
  const float* Sp = Sc + ((size_t)stream*NCHUNK + c)*4096;
  float s[64];
  #pragma unroll
  for (int n = 0; n < 64; ++n) s[n] = Sp[n*64 + lane];
  int t0 = c * CHUNK;
  for (int tt = 0; tt < CHUNK; ++tt){
    size_t idx = ((size_t)(b*1024 + t0 + tt))*AA + hh*64 + lane;
    float rt = rb[idx], kt = kb[idx], vt = vb[idx], wt = wb[idx];
    __syncthreads();
    rs[lane] = rt; ks[lane] = kt; ws[lane] = wt;
    __syncthreads();
    float o0 = 0.f, o1 = 0.f;
    #pragma unroll
    for (int n = 0; n < 64; n += 2){
      float kv0 = ks[n]*vt;
      o0 = fmaf(rs[n], fmaf(us[n], kv0, s[n]), o0);
      s[n] = fmaf(ws[n], s[n], kv0);
      float kv1 = ks[n+1]*vt;
      o1 = fmaf(rs[n+1], fmaf(us[n+1], kv1, s[n+1]), o1);
      s[n+1] = fmaf(ws[n+1], s[n+1], kv1);
    }
    ob[idx] = o0 + o1;
  }
}

// ---------------- group-norm over heads + silu(g) gate -> ao (f32) ----------------
__global__ __launch_bounds__(256) void k_gnorm_gate(
    const float* __restrict__ ob, const float* __restrict__ gb,
    const float* __restrict__ lg, const float* __restrict__ lb, float* __restrict__ ao){
  int t = blockIdx.x, tid = threadIdx.x;
  int lane = tid & 63, wid = tid >> 6;
  #pragma unroll
  for (int i = 0; i < 4; ++i){
    int head = wid*4 + i;
    int cidx = head*64 + lane;
    size_t idx = (size_t)t*AA + cidx;
    float v = ob[idx];
    float s1 = v, s2 = v*v;
    #pragma unroll
    for (int o = 32; o > 0; o >>= 1){
      s1 += __shfl_xor(s1, o, 64);
      s2 += __shfl_xor(s2, o, 64);
    }
    float m   = s1 * (1.f/64.f);
    float var = s2 * (1.f/64.f) - m*m;
    float nv  = (v - m) * rsqrtf(var + 6.4e-4f) * lg[cidx] + lb[cidx]; // eps=1e-5*64
    float gv  = gb[idx];
    float gate = gv / (1.f + expf(-gv));  // silu
    ao[idx] = nv * gate;
  }
}

// ---------------- ln2 + ffn token-shift mix -> zfr,zfk (bf16 scratch) ----------------
// x2 is virtual: x2[t] = xr[t] + at[t]
__global__ __launch_bounds__(256) void k_ln2mix(
    const float* __restrict__ xr, const float* __restrict__ at,
    const float* __restrict__ g2, const float* __restrict__ b2v,
    const float* __restrict__ fmaa_r, const float* __restrict__ fmaa_k,
    bf16* __restrict__ zfr, bf16* __restrict__ zfk){
  __shared__ float red[8];
  int t = blockIdx.x, tid = threadIdx.x;
  int tb = t & 1023;
  float cur[4], prv[4];
  #pragma unroll
  for (int i = 0; i < 4; ++i){
    int c = tid + 256*i;
    cur[i] = xr[(size_t)t*CC + c] + at[(size_t)t*CC + c];
    prv[i] = tb ? (xr[(size_t)(t-1)*CC + c] + at[(size_t)(t-1)*CC + c]) : 0.f;
  }
  float m1 = block_sum256(cur[0]+cur[1]+cur[2]+cur[3], red) * (1.f/CC);
  float vs = 0.f;
  #pragma unroll
  for (int i = 0; i < 4; ++i){ float d = cur[i]-m1; vs += d*d; }
  float inv1 = rsqrtf(block_sum256(vs, red)*(1.f/CC) + 1e-5f);
  float m2 = block_sum256(prv[0]+prv[1]+prv[2]+prv[3], red) * (1.f/CC);
  vs = 0.f;
  #pragma unroll
  for (int i = 0; i < 4; ++i){ float d = prv[i]-m2; vs += d*d; }
  float inv2 = rsqrtf(block_sum256(vs, red)*(1.f/CC) + 1e-5f);
  #pragma unroll
  for (int i = 0; i < 4; ++i){
    int c = tid + 256*i;
    float hc = (cur[i]-m1)*inv1*g2[c] + b2v[c];
    float hp = tb ? ((prv[i]-m2)*inv2*g2[c] + b2v[c]) : 0.f;
    float d = hp - hc;
    zfr[(size_t)t*CC + c] = f2b(hc + d * fmaa_r[c]);
    zfk[(size_t)t*CC + c] = f2b(hc + d * fmaa_k[c]);
  }
}

// ---------------- expert routing: deterministic stable counting sort ----------------
__global__ __launch_bounds__(512) void k_route(
    const int* __restrict__ ids, int* __restrict__ rowmap,
    int* __restrict__ counts, int* __restrict__ offsets){
  int wid = threadIdx.x >> 6, lane = threadIdx.x & 63;
  int e = wid;                 // expert handled by this wave
  __shared__ int cnt_s[8];
  int c = 0;
  for (int t0 = 0; t0 < BTOK; t0 += 64){
    int a = (ids[t0 + lane] * 5099) & 7;
    unsigned long long m = __ballot(a == e);
    c += __popcll(m);
  }
  if (lane == 0) cnt_s[e] = c;
  __syncthreads();
  int off = 0;
  for (int i = 0; i < e; ++i) off += cnt_s[i];
  if (lane == 0){ counts[e] = cnt_s[e]; offsets[e] = off; }
  int pos = off;
  for (int t0 = 0; t0 < BTOK; t0 += 64){
    int t = t0 + lane;
    int a = (ids[t] * 5099) & 7;
    unsigned long long m = __ballot(a == e);
    if (a == e){
      int r = __popcll(m & ((1ull << lane) - 1ull));
      rowmap[pos + r] = t;
    }
    pos += __popcll(m);
  }
}

// ---------------- small elementwise ----------------
__global__ void k_tanh_f(const float* __restrict__ in, float* __restrict__ out, int n){
  int i = blockIdx.x*256 + threadIdx.x;
  if (i >= n) return;
  out[i] = tanhf(in[i]);
}
__global__ void k_transpose_f(const float* __restrict__ in, float* __restrict__ out, int R, int Ccol){
  int idx = blockIdx.x*256 + threadIdx.x;
  if (idx >= R*Ccol) return;
  int r = idx / Ccol, c = idx % Ccol;
  out[c*R + r] = in[idx];
}
__global__ void k_final(const float* __restrict__ xr, const float* __restrict__ at,
                        const float* __restrict__ rr, const float* __restrict__ val,
                        float* __restrict__ out, int n){
  int i = blockIdx.x*256 + threadIdx.x;
  if (i >= n) return;
  float r = 1.f / (1.f + expf(-rr[i]));
  out[i] = xr[i] + at[i] + r*val[i];
}

// ---------------- launch ----------------
extern "C" void kernel_launch(void* const* d_in, const int* in_sizes, int n_in,
                              void* d_out, int out_size, void* d_ws, size_t ws_size,
                              hipStream_t stream) {
  const float* hidden  = (const float*)d_in[0];
  const int*   ids     = (const int*)  d_in[1];
  const float* pre_g   = (const float*)d_in[2];
  const float* pre_b   = (const float*)d_in[3];
  const float* ln1_g   = (const float*)d_in[4];
  const float* ln1_b   = (const float*)d_in[5];
  const float* ln2_g   = (const float*)d_in[6];
  const float* ln2_b   = (const float*)d_in[7];
  const float* maa_x   = (const float*)d_in[8];
  const float* maa_w   = (const float*)d_in[9];
  const float* maa_k   = (const float*)d_in[10];
  const float* maa_v   = (const float*)d_in[11];
  const float* maa_r   = (const float*)d_in[12];
  const float* maa_g   = (const float*)d_in[13];
  const float* maa_w1  = (const float*)d_in[14];
  const float* maa_w2  = (const float*)d_in[15];
  const float* att_td  = (const float*)d_in[16];
  const float* td_w1   = (const float*)d_in[17];
  const float* td_w2   = (const float*)d_in[18];
  const float* att_u   = (const float*)d_in[19];
  const float* att_wr  = (const float*)d_in[20];
  const float* att_wk  = (const float*)d_in[21];
  const float* att_wv  = (const float*)d_in[22];
  const float* att_wg  = (const float*)d_in[23];
  const float* att_wo  = (const float*)d_in[24];
  const float* lnx_g   = (const float*)d_in[25];
  const float* lnx_b   = (const float*)d_in[26];
  const float* fmaa_k  = (const float*)d_in[27];
  const float* fmaa_r  = (const float*)d_in[28];
  const float* ffn_wr  = (const float*)d_in[29];
  const float* sh_wk   = (const float*)d_in[30];
  const float* sh_wv   = (const float*)d_in[31];
  const float* ex_wk   = (const float*)d_in[32];
  const float* ex_wv   = (const float*)d_in[33];
  (void)ws_size; (void)n_in; (void)in_sizes; (void)out_size;

  // ---- workspace layout: 8 x 8 MiB planes, total EXACTLY 64 MiB (unchanged) ----
  char* base = (char*)d_ws;
  const size_t MiB = 1024ull*1024ull;
  float* x      = (float*)(base + 0*MiB);
  float* h      = (float*)(base + 8*MiB);
  float* rbuf   = h;
  float* kbuf   = (float*)(base + 16*MiB);
  float* vbuf   = (float*)(base + 24*MiB);
  unsigned short* hk2 = (unsigned short*)(base + 16*MiB);  // 16..30 MiB
  int*   rowmap = (int*)(base + 31*MiB);
  int*   counts = rowmap + BTOK;
  int*   offsets= counts + 64;
  float* gbuf   = (float*)(base + 32*MiB);
  float* val    = gbuf;
  bf16*  zw     = (bf16*)(base + 40*MiB);
  bf16*  zk     = (bf16*)(base + 44*MiB);
  float* tdbuf  = (float*)(base + 40*MiB);
  float* Ac     = (float*)(base + 40*MiB);
  float* wkvout = (float*)(base + 40*MiB);
  float* attout = (float*)(base + 40*MiB);
  bf16*  zr     = (bf16*)(base + 48*MiB);
  bf16*  zg     = (bf16*)(base + 52*MiB);
  float* wbuf   = (float*)(base + 48*MiB);
  float* ao     = (float*)(base + 48*MiB);
  float* recraw = (float*)(base + 48*MiB);
  bf16*  zv     = (bf16*)(base + 56*MiB);
  float* tdw1T  = (float*)(base + 60*MiB);
  float* tdw2T  = (float*)(base + 60*MiB + 256*1024);
  float* tmp64  = (float*)(base + 60*MiB + 512*1024);
  float* tanh64 = (float*)(base + 61*MiB);
  float* chunkS = (float*)(base + 56*MiB);
  bf16*  zfr    = (bf16*)(base + 56*MiB);
  bf16*  zfk    = (bf16*)(base + 60*MiB);

  // 1. pre_ln + ln1
  k_ln_pre<<<BTOK, 256, 0, stream>>>(hidden, pre_g, pre_b, ln1_g, ln1_b, x, h);
  // 2. attention maa mix -> z_{w,k,v,r,g}
  k_mix_att<<<BTOK, 256, 0, stream>>>(h, maa_x, maa_w1, maa_w2,
                                      maa_w, maa_k, maa_v, maa_r, maa_g,
                                      zw, zk, zv, zr, zg);
  // 3. r,k,v,g projections (MFMA, 64x64 tiles -> 512 blocks each)
  dim3 gP(CC/GN, BTOK/GM);   // (16,32)
  k_mgemm<0,0><<<gP, 256, 0, stream>>>(zr, att_wr, rbuf, nullptr, AA, CC);
  k_mgemm<0,0><<<gP, 256, 0, stream>>>(zk, att_wk, kbuf, nullptr, AA, CC);
  k_mgemm<0,0><<<gP, 256, 0, stream>>>(zv, att_wv, vbuf, nullptr, AA, CC);
  k_mgemm<0,0><<<gP, 256, 0, stream>>>(zg, att_wg, gbuf, nullptr, AA, CC);
  // 4. td path (small K/N -> keep VALU f32 for precision; negligible time)
  k_transpose_f<<<(CC*64 + 255)/256, 256, 0, stream>>>(td_w1, tdw1T, CC, 64);
  k_transpose_f<<<(64*AA + 255)/256, 256, 0, stream>>>(td_w2, tdw2T, 64, AA);
  k_gemm<bf16><<<dim3(1, BTOK/BM), 256, 0, stream>>>(zw, tdw1T, tmp64, nullptr, BTOK, 64, CC, 0);
  k_tanh_f<<<(BTOK*64 + 255)/256, 256, 0, stream>>>(tmp64, tanh64, BTOK*64);
  k_gemm<float><<<dim3(AA/BN, BTOK/BM), 256, 0, stream>>>(tanh64, tdw2T, tdbuf, nullptr, BTOK, AA, 64, 0);
  // 5. chunk-parallel WKV
  k_wprep<<<(BTOK*AA + 255)/256, 256, 0, stream>>>(tdbuf, att_td, wbuf, BTOK*AA);
  k_wkv_chunk<<<32*NCHUNK, 64, 0, stream>>>(kbuf, vbuf, wbuf, chunkS, Ac);
  k_wkv_combine<<<32, 64, 0, stream>>>(chunkS, Ac);
  k_wkv_out<<<32*NCHUNK, 64, 0, stream>>>(rbuf, kbuf, vbuf, wbuf, att_u, chunkS, wkvout);
  // 6. group-norm + silu gate -> ao
  k_gnorm_gate<<<BTOK, 256, 0, stream>>>(wkvout, gbuf, lnx_g, lnx_b, ao);
  // 7. output proj -> attout (A is f32: cvt in staging)
  k_mgemm<1,0><<<gP, 256, 0, stream>>>(ao, att_wo, attout, nullptr, CC, AA);
  // 8. ln2 + ffn mix
  k_ln2mix<<<BTOK, 256, 0, stream>>>(x, attout, ln2_g, ln2_b, fmaa_r, fmaa_k, zfr, zfk);
  // 9. receptance
  k_mgemm<0,0><<<gP, 256, 0, stream>>>(zfr, ffn_wr, recraw, nullptr, CC, CC);
  // 10. shared expert
  k_mgemm<0,1><<<dim3(IDIM/GN, BTOK/GM), 256, 0, stream>>>(zfk, sh_wk, nullptr, hk2, IDIM, CC);
  k_mgemm<0,0><<<gP, 256, 0, stream>>>(hk2, sh_wv, val, nullptr, CC, IDIM);
  // 11. routed experts (x = row-tile so dead blocks exit fast; weight-sharing blocks adjacent)
  k_route<<<1, 512, 0, stream>>>(ids, rowmap, counts, offsets);
  k_mgemm_moe<0><<<dim3(BTOK/GM, IDIM/GN, NEXP), 256, 0, stream>>>(
      (const unsigned short*)zfk, ex_wk, (size_t)IDIM*CC, nullptr, hk2, IDIM, CC,
      rowmap, counts, offsets);
  k_mgemm_moe<1><<<dim3(BTOK/GM, CC/GN, NEXP), 256, 0, stream>>>(
      hk2, ex_wv, (size_t)CC*IDIM, val, nullptr, CC, IDIM,
      rowmap, counts, offsets);
  // 12. final combine -> f32 out
  k_final<<<(BTOK*CC + 255)/256, 256, 0, stream>>>(x, attout, recraw, val, (float*)d_out, BTOK*CC);
}

// Round 4
// 1632.882 us; speedup vs baseline: 1.0923x; 1.0923x over previous
//
#include <hip/hip_runtime.h>
#include <hip/hip_bf16.h>

typedef __hip_bfloat16 bf16;

__device__ __forceinline__ float b2f(bf16 x){ return __bfloat162float(x); }
__device__ __forceinline__ bf16  f2b(float x){ return __float2bfloat16(x); }
__device__ __forceinline__ float ldA(const float* p){ return *p; }
__device__ __forceinline__ float ldA(const bf16* p){ return b2f(*p); }

#define BTOK 2048
#define CC 1024
#define AA 1024
#define IDIM 3584
#define NEXP 8
#define CHUNK 64
#define NCHUNK 16   // 1024 / CHUNK

// ---------------- MFMA types / helpers ----------------
typedef __attribute__((ext_vector_type(8))) short   s8v;   // 8 bf16 bit-patterns
typedef __attribute__((ext_vector_type(8))) __bf16  b8v;   // MFMA A/B fragment
typedef __attribute__((ext_vector_type(4))) float   f4v;   // MFMA C/D fragment

__device__ __forceinline__ unsigned short f2bf_bits(float f){   // RNE, matches __float2bfloat16
  unsigned u = __builtin_bit_cast(unsigned, f);
  u += 0x7fffu + ((u >> 16) & 1u);
  return (unsigned short)(u >> 16);
}

// async global->LDS, 16B per lane; dest must be wave-lane-linear (it is: base + tid*16)
#define GLDS16(g, l) __builtin_amdgcn_global_load_lds( \
    (const __attribute__((address_space(1))) void*)(g), \
    (__attribute__((address_space(3)))       void*)(l), 16, 0, 0)

// ---------------- reductions ----------------
__device__ __forceinline__ float block_sum256(float v, float* red){
  #pragma unroll
  for (int o = 32; o > 0; o >>= 1) v += __shfl_down(v, o, 64);
  int lane = threadIdx.x & 63, wid = threadIdx.x >> 6;
  if (lane == 0) red[wid] = v;
  __syncthreads();
  float s = red[0] + red[1] + red[2] + red[3];
  __syncthreads();
  return s;
}

// ---------------- fused pre_ln + ln1 (f32 in, f32 out) ----------------
__global__ __launch_bounds__(256) void k_ln_pre(
    const float* __restrict__ hidden,
    const float* __restrict__ g0, const float* __restrict__ b0,
    const float* __restrict__ g1, const float* __restrict__ b1,
    float* __restrict__ xout, float* __restrict__ hout){
  __shared__ float red[8];
  int t = blockIdx.x, tid = threadIdx.x;
  const float* src = hidden + (size_t)t * CC;
  float v[4];
  #pragma unroll
  for (int i = 0; i < 4; ++i) v[i] = src[tid + 256*i];
  float mean = block_sum256(v[0]+v[1]+v[2]+v[3], red) * (1.f/CC);
  float vs = 0.f;
  #pragma unroll
  for (int i = 0; i < 4; ++i){ float d = v[i]-mean; vs += d*d; }
  float var = block_sum256(vs, red) * (1.f/CC);
  float inv = rsqrtf(var + 1e-5f);
  float xv[4];
  #pragma unroll
  for (int i = 0; i < 4; ++i){
    int c = tid + 256*i;
    xv[i] = (v[i]-mean)*inv*g0[c] + b0[c];
    xout[(size_t)t*CC + c] = xv[i];
  }
  float mean2 = block_sum256(xv[0]+xv[1]+xv[2]+xv[3], red) * (1.f/CC);
  vs = 0.f;
  #pragma unroll
  for (int i = 0; i < 4; ++i){ float d = xv[i]-mean2; vs += d*d; }
  float var2 = block_sum256(vs, red) * (1.f/CC);
  float inv2 = rsqrtf(var2 + 1e-5f);
  #pragma unroll
  for (int i = 0; i < 4; ++i){
    int c = tid + 256*i;
    hout[(size_t)t*CC + c] = (xv[i]-mean2)*inv2*g1[c] + b1[c];
  }
}

// ---------------- token-shift + maa mix -> z_{w,k,v,r,g} (bf16 scratch) ----------------
__global__ __launch_bounds__(256) void k_mix_att(
    const float* __restrict__ h,
    const float* __restrict__ maa_x, const float* __restrict__ w1, const float* __restrict__ w2,
    const float* __restrict__ maa_w, const float* __restrict__ maa_k, const float* __restrict__ maa_v,
    const float* __restrict__ maa_r, const float* __restrict__ maa_g,
    bf16* __restrict__ zw, bf16* __restrict__ zk, bf16* __restrict__ zv,
    bf16* __restrict__ zr, bf16* __restrict__ zg){
  int t = blockIdx.x, tid = threadIdx.x;
  int tb = t & 1023;  // position within batch (T=1024)
  __shared__ float hs[CC], xxs[CC], xxxs[CC], t160[160];
  #pragma unroll
  for (int i = 0; i < 4; ++i){
    int c = tid + 256*i;
    float hv = h[(size_t)t*CC + c];
    float pv = tb ? h[(size_t)(t-1)*CC + c] : 0.f;
    float xx = pv - hv;
    hs[c] = hv; xxs[c] = xx;
    xxxs[c] = hv + xx * maa_x[c];
  }
  __syncthreads();
  if (tid < 160){
    float acc = 0.f;
    for (int c = 0; c < CC; ++c) acc = fmaf(xxxs[c], w1[c*160 + tid], acc);
    t160[tid] = tanhf(acc);
  }
  __syncthreads();
  const float* maas[5] = {maa_w, maa_k, maa_v, maa_r, maa_g};
  bf16* zs[5] = {zw, zk, zv, zr, zg};
  #pragma unroll
  for (int f = 0; f < 5; ++f){
    #pragma unroll
    for (int i = 0; i < 4; ++i){
      int c = tid + 256*i;
      float acc = 0.f;
      #pragma unroll
      for (int d = 0; d < 32; ++d)
        acc = fmaf(t160[f*32 + d], w2[(size_t)(f*32 + d)*CC + c], acc);
      float z = hs[c] + xxs[c] * (maas[f][c] + acc);
      zs[f][(size_t)t*CC + c] = f2b(z);
    }
  }
}

// ---------------- small VALU GEMM (td path only) ----------------
#define BM 64
#define BN 64
#define BK 16
template <typename TA>
__global__ __launch_bounds__(256) void k_gemm(
    const TA* __restrict__ A, const float* __restrict__ W,
    float* __restrict__ Of32, bf16* __restrict__ Obf,
    int M, int N, int K, int epi){
  __shared__ float As[BK][BM+1];
  __shared__ float Bs[BK][BN+1];
  int bn = blockIdx.x * BN, bm = blockIdx.y * BM;
  int tid = threadIdx.x;
  int tx = tid & 15, ty = tid >> 4;
  int lr = tid >> 2;
  int lk = (tid & 3) * 4;
  const TA*    Ap = A + (size_t)(bm + lr)*K + lk;
  const float* Wp = W + (size_t)(bn + lr)*K + lk;
  float acc[4][4] = {};
  for (int k0 = 0; k0 < K; k0 += BK){
    #pragma unroll
    for (int j = 0; j < 4; ++j){
      As[lk+j][lr] = ldA(Ap + k0 + j);
      Bs[lk+j][lr] = Wp[k0 + j];
    }
    __syncthreads();
    #pragma unroll
    for (int kk = 0; kk < BK; ++kk){
      float av[4], bv[4];
      #pragma unroll
      for (int i = 0; i < 4; ++i) av[i] = As[kk][ty*4 + i];
      #pragma unroll
      for (int j = 0; j < 4; ++j) bv[j] = Bs[kk][tx*4 + j];
      #pragma unroll
      for (int i = 0; i < 4; ++i)
        #pragma unroll
        for (int j = 0; j < 4; ++j) acc[i][j] = fmaf(av[i], bv[j], acc[i][j]);
    }
    __syncthreads();
  }
  #pragma unroll
  for (int i = 0; i < 4; ++i){
    int row = bm + ty*4 + i;
    #pragma unroll
    for (int j = 0; j < 4; ++j){
      int col = bn + tx*4 + j;
      size_t oi = (size_t)row*N + col;
      float v = acc[i][j];
      if (epi == 0){ Of32[oi] = v; }
      else { v = v > 0.f ? v : 0.f; Obf[oi] = f2b(v*v); }
    }
  }
}

// ================= m97-style MFMA GEMM: O[M,N] = A[M,K] @ W[N,K]^T =================
// 128x128x32 tile, 4 waves (2x2), wave = 64x64 = 4x4 frags of 16x16x32 bf16.
// Staging via global_load_lds width-16 (cannot be sunk by compiler; loads live in vmcnt).
// A: bf16, LDS [128][32] linear (m97-proven layout).  W: f32, LDS [128][32] f32 with
// XOR-source-swizzle chunk^=(row&7) (16B chunks) to kill the 128B-row 16-way bank
// conflict on frag reads; read side applies same XOR (involution).  W converted
// f32->bf16 at frag read (RNE, identical numerics to prior rounds).
// frag maps [m89/m91]: A row=l&15, k=(l>>4)*8+j ; B col=l&15 ; C/D col=l&15, row=(l>>4)*4+reg.
struct MGB { const void* A[4]; const float* W[4]; void* O[4]; };

template<int AF32, int EPI, int SPLITK, int NB>   // EPI: 0 store f32, 1 relu^2->bf16, 2 atomicAdd f32
__global__ __launch_bounds__(256) void k_mg(MGB args, int N, int K){
  constexpr int ABYTES = AF32 ? 16384 : 8192;
  __shared__ char lds[ABYTES + 16384];
  unsigned short* As  = (unsigned short*)lds;     // bf16 [128][32] linear
  float*          AsF = (float*)lds;              // f32  [128][32] swizzled
  float*          BsF = (float*)(lds + ABYTES);   // f32  [128][32] swizzled

  const int bz = blockIdx.z;
  const int bi = bz / SPLITK, kh = bz % SPLITK;
  const int Kh = K / SPLITK, kbeg = kh * Kh;
  const unsigned short* Ab = (const unsigned short*)args.A[bi];
  const float*          Af = (const float*)args.A[bi];
  const float*          W  = args.W[bi];
  const int bm = blockIdx.y*128, bn = blockIdx.x*128;
  const int tid = threadIdx.x, l = tid & 63, w = tid >> 6;
  const int mr = (w >> 1)*64, nc = (w & 1)*64;
  const int r4 = tid >> 2, c4 = tid & 3;          // bf16 A staging: row r4(+64), chunk c4 (8 bf16)
  const int r8 = tid >> 3, c8 = tid & 7;          // f32 staging: row s*32+r8, chunk c8 (4 f32)

  f4v acc[4][4];
  #pragma unroll
  for (int i = 0; i < 4; ++i)
    #pragma unroll
    for (int j = 0; j < 4; ++j){ f4v z = {0.f,0.f,0.f,0.f}; acc[i][j] = z; }

  const int nk = Kh / 32;
  for (int kt = 0; kt < nk; ++kt){
    const int kk = kbeg + kt*32;
    __syncthreads();                              // prior step's frag reads done
    if (!AF32){
      GLDS16(Ab + (size_t)(bm + r4      )*K + kk + c4*8, (char*)As + tid*16);
      GLDS16(Ab + (size_t)(bm + 64 + r4 )*K + kk + c4*8, (char*)As + 4096 + tid*16);
    } else {
      #pragma unroll
      for (int s = 0; s < 4; ++s){
        int r = s*32 + r8, cs = c8 ^ (r & 7);
        GLDS16(Af + (size_t)(bm + r)*K + kk + cs*4, (char*)AsF + s*4096 + tid*16);
      }
    }
    #pragma unroll
    for (int s = 0; s < 4; ++s){
      int r = s*32 + r8, cs = c8 ^ (r & 7);
      GLDS16(W + (size_t)(bn + r)*K + kk + cs*4, (char*)BsF + s*4096 + tid*16);
    }
    __syncthreads();                              // compiler drains vmcnt(0) here -> tile ready
    b8v afr[4], bfr[4];
    #pragma unroll
    for (int f = 0; f < 4; ++f){
      if (!AF32){
        afr[f] = *(const b8v*)&As[(mr + f*16 + (l&15))*32 + (l>>4)*8];
      } else {
        int row = mr + f*16 + (l&15), s = row & 7, p = (2*(l>>4)) ^ s;
        f4v q0 = *(const f4v*)&AsF[row*32 + p*4];
        f4v q1 = *(const f4v*)&AsF[row*32 + (p^1)*4];
        s8v t;
        #pragma unroll
        for (int j = 0; j < 4; ++j){ t[j] = (short)f2bf_bits(q0[j]); t[4+j] = (short)f2bf_bits(q1[j]); }
        afr[f] = __builtin_bit_cast(b8v, t);
      }
      {
        int row = nc + f*16 + (l&15), s = row & 7, p = (2*(l>>4)) ^ s;
        f4v q0 = *(const f4v*)&BsF[row*32 + p*4];
        f4v q1 = *(const f4v*)&BsF[row*32 + (p^1)*4];
        s8v t;
        #pragma unroll
        for (int j = 0; j < 4; ++j){ t[j] = (short)f2bf_bits(q0[j]); t[4+j] = (short)f2bf_bits(q1[j]); }
        bfr[f] = __builtin_bit_cast(b8v, t);
      }
    }
    #pragma unroll
    for (int fr = 0; fr < 4; ++fr)
      #pragma unroll
      for (int fc = 0; fc < 4; ++fc)
        acc[fr][fc] = __builtin_amdgcn_mfma_f32_16x16x32_bf16(afr[fr], bfr[fc], acc[fr][fc], 0, 0, 0);
  }
  const int rb = bm + mr + ((l >> 4) << 2);
  const int cb = bn + nc + (l & 15);
  #pragma unroll
  for (int fr = 0; fr < 4; ++fr)
    #pragma unroll
    for (int fc = 0; fc < 4; ++fc)
      #pragma unroll
      for (int j = 0; j < 4; ++j){
        size_t oi = (size_t)(rb + fr*16 + j)*N + (cb + fc*16);
        float v = acc[fr][fc][j];
        if (EPI == 0)      ((float*)args.O[bi])[oi] = v;
        else if (EPI == 1){ v = v > 0.f ? v : 0.f; ((unsigned short*)args.O[bi])[oi] = f2bf_bits(v*v); }
        else               atomicAdd((float*)args.O[bi] + oi, v);
      }
}

// ---------------- MoE MFMA GEMM (gather/scatter), same m97 structure ----------------
// MODE 0 (key): A rows gathered via rowmap, out compact rows, relu^2 -> bf16
// MODE 1 (value): A rows compact, out scattered via rowmap, atomicAdd f32 (split-K safe)
template<int MODE, int SPLITK>
__global__ __launch_bounds__(256) void k_mg_moe(
    const unsigned short* __restrict__ A, const float* __restrict__ Wbase, size_t wstride,
    float* __restrict__ Of32, unsigned short* __restrict__ Obf, int N, int K,
    const int* __restrict__ rowmap, const int* __restrict__ counts,
    const int* __restrict__ offsets){
  const int bz = blockIdx.z;
  const int e = bz / SPLITK, kh = bz % SPLITK;
  const int cnt = counts[e];
  const int mbase = blockIdx.x*128;
  if (mbase >= cnt) return;
  const int obase = offsets[e];
  const float* W = Wbase + (size_t)e*wstride;
  const int Kh = K / SPLITK, kbeg = kh * Kh;
  __shared__ char lds[8192 + 16384];
  unsigned short* As  = (unsigned short*)lds;
  float*          BsF = (float*)(lds + 8192);
  const int tid = threadIdx.x, l = tid & 63, w = tid >> 6;
  const int bn = blockIdx.y*128;
  const int mr = (w >> 1)*64, nc = (w & 1)*64;
  const int r4 = tid >> 2, c4 = tid & 3;
  const int r8 = tid >> 3, c8 = tid & 7;

  int grow[2];
  #pragma unroll
  for (int s = 0; s < 2; ++s){
    int lr = mbase + s*64 + r4;
    lr = lr < cnt ? lr : cnt - 1;                 // clamp: garbage rows masked at epilogue
    grow[s] = (MODE == 0) ? rowmap[obase + lr] : (obase + lr);
  }

  f4v acc[4][4];
  #pragma unroll
  for (int i = 0; i < 4; ++i)
    #pragma unroll
    for (int j = 0; j < 4; ++j){ f4v z = {0.f,0.f,0.f,0.f}; acc[i][j] = z; }

  const int nk = Kh / 32;
  for (int kt = 0; kt < nk; ++kt){
    const int kk = kbeg + kt*32;
    __syncthreads();
    GLDS16(A + (size_t)grow[0]*K + kk + c4*8, (char*)As + tid*16);
    GLDS16(A + (size_t)grow[1]*K + kk + c4*8, (char*)As + 4096 + tid*16);
    #pragma unroll
    for (int s = 0; s < 4; ++s){
      int r = s*32 + r8, cs = c8 ^ (r & 7);
      GLDS16(W + (size_t)(bn + r)*K + kk + cs*4, (char*)BsF + s*4096 + tid*16);
    }
    __syncthreads();
    b8v afr[4], bfr[4];
    #pragma unroll
    for (int f = 0; f < 4; ++f){
      afr[f] = *(const b8v*)&As[(mr + f*16 + (l&15))*32 + (l>>4)*8];
      int row = nc + f*16 + (l&15), s = row & 7, p = (2*(l>>4)) ^ s;
      f4v q0 = *(const f4v*)&BsF[row*32 + p*4];
      f4v q1 = *(const f4v*)&BsF[row*32 + (p^1)*4];
      s8v t;
      #pragma unroll
      for (int j = 0; j < 4; ++j){ t[j] = (short)f2bf_bits(q0[j]); t[4+j] = (short)f2bf_bits(q1[j]); }
      bfr[f] = __builtin_bit_cast(b8v, t);
    }
    #pragma unroll
    for (int fr = 0; fr < 4; ++fr)
      #pragma unroll
      for (int fc = 0; fc < 4; ++fc)
        acc[fr][fc] = __builtin_amdgcn_mfma_f32_16x16x32_bf16(afr[fr], bfr[fc], acc[fr][fc], 0, 0, 0);
  }
  const int rb = mbase + mr + ((l >> 4) << 2);
  const int cb = bn + nc + (l & 15);
  #pragma unroll
  for (int fr = 0; fr < 4; ++fr)
    #pragma unroll
    for (int fc = 0; fc < 4; ++fc)
      #pragma unroll
      for (int j = 0; j < 4; ++j){
        int lrow = rb + fr*16 + j;
        if (lrow >= cnt) continue;
        int col = cb + fc*16;
        float v = acc[fr][fc][j];
        if (MODE == 0){
          size_t oi = (size_t)(obase + lrow)*N + col;
          v = v > 0.f ? v : 0.f;
          Obf[oi] = f2bf_bits(v*v);
        } else {
          int orow = rowmap[obase + lrow];
          atomicAdd(Of32 + (size_t)orow*N + col, v);
        }
      }
}

// ================= chunk-parallel WKV =================
__global__ void k_wprep(const float* __restrict__ td, const float* __restrict__ bias,
                        float* __restrict__ wbuf, int n){
  int i = blockIdx.x*256 + threadIdx.x;
  if (i >= n) return;
  wbuf[i] = expf(-expf(td[i] + bias[i & (AA-1)]));
}

__global__ __launch_bounds__(64) void k_wkv_chunk(
    const float* __restrict__ kb, const float* __restrict__ vb,
    const float* __restrict__ wb, float* __restrict__ Bc, float* __restrict__ Ac){
  int blk = blockIdx.x;
  int stream = blk >> 4, c = blk & (NCHUNK-1);
  int b = stream >> 4, hh = stream & 15;
  int lane = threadIdx.x;
  __shared__ float ks[64], ws[64];
  float s[64];
  #pragma unroll
  for (int n = 0; n < 64; ++n) s[n] = 0.f;
  float prod = 1.f;
  int t0 = c * CHUNK;
  for (int tt = 0; tt < CHUNK; ++tt){
    size_t idx = ((size_t)(b*1024 + t0 + tt))*AA + hh*64 + lane;
    float kt = kb[idx], vt = vb[idx], wt = wb[idx];
    __syncthreads();
    ks[lane] = kt; ws[lane] = wt;
    __syncthreads();
    prod *= wt;
    #pragma unroll
    for (int n = 0; n < 64; ++n)
      s[n] = fmaf(ws[n], s[n], ks[n]*vt);
  }
  float* Bp = Bc + ((size_t)stream*NCHUNK + c)*4096;
  #pragma unroll
  for (int n = 0; n < 64; ++n) Bp[n*64 + lane] = s[n];
  Ac[((size_t)stream*NCHUNK + c)*64 + lane] = prod;
}

__global__ __launch_bounds__(64) void k_wkv_combine(
    float* __restrict__ Bc, const float* __restrict__ Ac){
  int stream = blockIdx.x;
  int lane = threadIdx.x;
  __shared__ float as[64];
  float S[64];
  #pragma unroll
  for (int n = 0; n < 64; ++n) S[n] = 0.f;
  for (int c = 0; c < NCHUNK; ++c){
    __syncthreads();
    as[lane] = Ac[((size_t)stream*NCHUNK + c)*64 + lane];
    __syncthreads();
    float* Bp = Bc + ((size_t)stream*NCHUNK + c)*4096;
    #pragma unroll
    for (int n = 0; n < 64; ++n){
      float bcv = Bp[n*64 + lane];
      Bp[n*64 + lane] = S[n];
      S[n] = fmaf(as[n], S[n], bcv);
    }
  }
}

__global__ __launch_bounds__(64) void k_wkv_out(
    const float* __restrict__ rb, const float* __restrict__ kb,
    const float* __restrict__ vb, const float* __restrict__ wb,
    const float* __restrict__ u, const float* __restrict__ Sc,
    float* __restrict__ ob){
  int blk = blockIdx.x;
  int stream = blk >> 4, c = blk & (NCHUNK-1);
  int b = stream >> 4, hh = stream & 15;
  int lane = threadIdx.x;
  __shared__ float rs[64], ks[64], ws[64], us[64];
  us[lane] = u[hh*64 + lane];
  const float* Sp = Sc + ((size_t)stream*NCHUNK + c)*4096;
  float s[64];
  #pragma unroll
  for (int n = 0; n < 64; ++n) s[n] = Sp[n*64 + lane];
  int t0 = c * CHUNK;
  for (int tt = 0; tt < CHUNK; ++tt){
    size_t idx = ((size_t)(b*1024 + t0 + tt))*AA + hh*64 + lane;
    float rt = rb[idx], kt = kb[idx], vt = vb[idx], wt = wb[idx];
    __syncthreads();
    rs[lane] = rt; ks[lane] = kt; ws[lane] = wt;
    __syncthreads();
    float o0 = 0.f, o1 = 0.f;
    #pragma unroll
    for (int n = 0; n < 64; n += 2){
      float kv0 = ks[n]*vt;
      o0 = fmaf(rs[n], fmaf(us[n], kv0, s[n]), o0);
      s[n] = fmaf(ws[n], s[n], kv0);
      float kv1 = ks[n+1]*vt;
      o1 = fmaf(rs[n+1], fmaf(us[n+1], kv1, s[n+1]), o1);
      s[n+1] = fmaf(ws[n+1], s[n+1], kv1);
    }
    ob[idx] = o0 + o1;
  }
}

// ---------------- group-norm over heads + silu(g) gate -> ao (f32) ----------------
__global__ __launch_bounds__(256) void k_gnorm_gate(
    const float* __restrict__ ob, const float* __restrict__ gb,
    const float* __restrict__ lg, const float* __restrict__ lb, float* __restrict__ ao){
  int t = blockIdx.x, tid = threadIdx.x;
  int lane = tid & 63, wid = tid >> 6;
  #pragma unroll
  for (int i = 0; i < 4; ++i){
    int head = wid*4 + i;
    int cidx = head*64 + lane;
    size_t idx = (size_t)t*AA + cidx;
    float v = ob[idx];
    float s1 = v, s2 = v*v;
    #pragma unroll
    for (int o = 32; o > 0; o >>= 1){
      s1 += __shfl_xor(s1, o, 64);
      s2 += __shfl_xor(s2, o, 64);
    }
    float m   = s1 * (1.f/64.f);
    float var = s2 * (1.f/64.f) - m*m;
    float nv  = (v - m) * rsqrtf(var + 6.4e-4f) * lg[cidx] + lb[cidx];
    float gv  = gb[idx];
    float gate = gv / (1.f + expf(-gv));
    ao[idx] = nv * gate;
  }
}

// ---------------- ln2 + ffn token-shift mix -> zfr,zfk ----------------
__global__ __launch_bounds__(256) void k_ln2mix(
    const float* __restrict__ xr, const float* __restrict__ at,
    const float* __restrict__ g2, const float* __restrict__ b2v,
    const float* __restrict__ fmaa_r, const float* __restrict__ fmaa_k,
    bf16* __restrict__ zfr, bf16* __restrict__ zfk){
  __shared__ float red[8];
  int t = blockIdx.x, tid = threadIdx.x;
  int tb = t & 1023;
  float cur[4], prv[4];
  #pragma unroll
  for (int i = 0; i < 4; ++i){
    int c = tid + 256*i;
    cur[i] = xr[(size_t)t*CC + c] + at[(size_t)t*CC + c];
    prv[i] = tb ? (xr[(size_t)(t-1)*CC + c] + at[(size_t)(t-1)*CC + c]) : 0.f;
  }
  float m1 = block_sum256(cur[0]+cur[1]+cur[2]+cur[3], red) * (1.f/CC);
  float vs = 0.f;
  #pragma unroll
  for (int i = 0; i < 4; ++i){ float d = cur[i]-m1; vs += d*d; }
  float inv1 = rsqrtf(block_sum256(vs, red)*(1.f/CC) + 1e-5f);
  float m2 = block_sum256(prv[0]+prv[1]+prv[2]+prv[3], red) * (1.f/CC);
  vs = 0.f;
  #pragma unroll
  for (int i = 0; i < 4; ++i){ float d = prv[i]-m2; vs += d*d; }
  float inv2 = rsqrtf(block_sum256(vs, red)*(1.f/CC) + 1e-5f);
  #pragma unroll
  for (int i = 0; i < 4; ++i){
    int c = tid + 256*i;
    float hc = (cur[i]-m1)*inv1*g2[c] + b2v[c];
    float hp = tb ? ((prv[i]-m2)*inv2*g2[c] + b2v[c]) : 0.f;
    float d = hp - hc;
    zfr[(size_t)t*CC + c] = f2b(hc + d * fmaa_r[c]);
    zfk[(size_t)t*CC + c] = f2b(hc + d * fmaa_k[c]);
  }
}

// ---------------- expert routing: deterministic stable counting sort ----------------
__global__ __launch_bounds__(512) void k_route(
    const int* __restrict__ ids, int* __restrict__ rowmap,
    int* __restrict__ counts, int* __restrict__ offsets){
  int wid = threadIdx.x >> 6, lane = threadIdx.x & 63;
  int e = wid;
  __shared__ int cnt_s[8];
  int c = 0;
  for (int t0 = 0; t0 < BTOK; t0 += 64){
    int a = (ids[t0 + lane] * 5099) & 7;
    unsigned long long m = __ballot(a == e);
    c += __popcll(m);
  }
  if (lane == 0) cnt_s[e] = c;
  __syncthreads();
  int off = 0;
  for (int i = 0; i < e; ++i) off += cnt_s[i];
  if (lane == 0){ counts[e] = cnt_s[e]; offsets[e] = off; }
  int pos = off;
  for (int t0 = 0; t0 < BTOK; t0 += 64){
    int t = t0 + lane;
    int a = (ids[t] * 5099) & 7;
    unsigned long long m = __ballot(a == e);
    if (a == e){
      int r = __popcll(m & ((1ull << lane) - 1ull));
      rowmap[pos + r] = t;
    }
    pos += __popcll(m);
  }
}

// ---------------- small elementwise ----------------
__global__ void k_tanh_f(const float* __restrict__ in, float* __restrict__ out, int n){
  int i = blockIdx.x*256 + threadIdx.x;
  if (i >= n) return;
  out[i] = tanhf(in[i]);
}
__global__ void k_transpose_f(const float* __restrict__ in, float* __restrict__ out, int R, int Ccol){
  int idx = blockIdx.x*256 + threadIdx.x;
  if (idx >= R*Ccol) return;
  int r = idx / Ccol, c = idx % Ccol;
  out[c*R + r] = in[idx];
}
__global__ void k_zero(float* __restrict__ p, int n4){
  int i = blockIdx.x*256 + threadIdx.x;
  if (i >= n4) return;
  f4v z = {0.f,0.f,0.f,0.f};
  ((f4v*)p)[i] = z;
}
__global__ void k_final(const float* __restrict__ xr, const float* __restrict__ at,
                        const float* __restrict__ rr, const float* __restrict__ val,
                        float* __restrict__ out, int n){
  int i = blockIdx.x*256 + threadIdx.x;
  if (i >= n) return;
  float r = 1.f / (1.f + expf(-rr[i]));
  out[i] = xr[i] + at[i] + r*val[i];
}

// ---------------- launch ----------------
extern "C" void kernel_launch(void* const* d_in, const int* in_sizes, int n_in,
                              void* d_out, int out_size, void* d_ws, size_t ws_size,
                              hipStream_t stream) {
  const float* hidden  = (const float*)d_in[0];
  const int*   ids     = (const int*)  d_in[1];
  const float* pre_g   = (const float*)d_in[2];
  const float* pre_b   = (const float*)d_in[3];
  const float* ln1_g   = (const float*)d_in[4];
  const float* ln1_b   = (const float*)d_in[5];
  const float* ln2_g   = (const float*)d_in[6];
  const float* ln2_b   = (const float*)d_in[7];
  const float* maa_x   = (const float*)d_in[8];
  const float* maa_w   = (const float*)d_in[9];
  const float* maa_k   = (const float*)d_in[10];
  const float* maa_v   = (const float*)d_in[11];
  const float* maa_r   = (const float*)d_in[12];
  const float* maa_g   = (const float*)d_in[13];
  const float* maa_w1  = (const float*)d_in[14];
  const float* maa_w2  = (const float*)d_in[15];
  const float* att_td  = (const float*)d_in[16];
  const float* td_w1   = (const float*)d_in[17];
  const float* td_w2   = (const float*)d_in[18];
  const float* att_u   = (const float*)d_in[19];
  const float* att_wr  = (const float*)d_in[20];
  const float* att_wk  = (const float*)d_in[21];
  const float* att_wv  = (const float*)d_in[22];
  const float* att_wg  = (const float*)d_in[23];
  const float* att_wo  = (const float*)d_in[24];
  const float* lnx_g   = (const float*)d_in[25];
  const float* lnx_b   = (const float*)d_in[26];
  const float* fmaa_k  = (const float*)d_in[27];
  const float* fmaa_r  = (const float*)d_in[28];
  const float* ffn_wr  = (const float*)d_in[29];
  const float* sh_wk   = (const float*)d_in[30];
  const float* sh_wv   = (const float*)d_in[31];
  const float* ex_wk   = (const float*)d_in[32];
  const float* ex_wv   = (const float*)d_in[33];
  (void)ws_size; (void)n_in; (void)in_sizes; (void)out_size;

  // ---- workspace layout: 8 x 8 MiB planes, total EXACTLY 64 MiB (unchanged) ----
  char* base = (char*)d_ws;
  const size_t MiB = 1024ull*1024ull;
  float* x      = (float*)(base + 0*MiB);
  float* h      = (float*)(base + 8*MiB);
  float* rbuf   = h;
  float* kbuf   = (float*)(base + 16*MiB);
  float* vbuf   = (float*)(base + 24*MiB);
  unsigned short* hk2 = (unsigned short*)(base + 16*MiB);  // 16..30 MiB
  int*   rowmap = (int*)(base + 31*MiB);
  int*   counts = rowmap + BTOK;
  int*   offsets= counts + 64;
  float* gbuf   = (float*)(base + 32*MiB);
  float* val    = gbuf;
  bf16*  zw     = (bf16*)(base + 40*MiB);
  bf16*  zk     = (bf16*)(base + 44*MiB);
  float* tdbuf  = (float*)(base + 40*MiB);
  float* Ac     = (float*)(base + 40*MiB);
  float* wkvout = (float*)(base + 40*MiB);
  float* attout = (float*)(base + 40*MiB);
  bf16*  zr     = (bf16*)(base + 48*MiB);
  bf16*  zg     = (bf16*)(base + 52*MiB);
  float* wbuf   = (float*)(base + 48*MiB);
  float* ao     = (float*)(base + 48*MiB);
  float* recraw = (float*)(base + 48*MiB);
  bf16*  zv     = (bf16*)(base + 56*MiB);
  float* tdw1T  = (float*)(base + 60*MiB);
  float* tdw2T  = (float*)(base + 60*MiB + 256*1024);
  float* tmp64  = (float*)(base + 60*MiB + 512*1024);
  float* tanh64 = (float*)(base + 61*MiB);
  float* chunkS = (float*)(base + 56*MiB);
  bf16*  zfr    = (bf16*)(base + 56*MiB);
  bf16*  zfk    = (bf16*)(base + 60*MiB);

  // 1. pre_ln + ln1
  k_ln_pre<<<BTOK, 256, 0, stream>>>(hidden, pre_g, pre_b, ln1_g, ln1_b, x, h);
  // 2. attention maa mix
  k_mix_att<<<BTOK, 256, 0, stream>>>(h, maa_x, maa_w1, maa_w2,
                                      maa_w, maa_k, maa_v, maa_r, maa_g,
                                      zw, zk, zv, zr, zg);
  // 3. r,k,v,g projections: ONE z-batched dispatch, 512 blocks
  {
    MGB a{};
    a.A[0]=zr; a.A[1]=zk; a.A[2]=zv; a.A[3]=zg;
    a.W[0]=att_wr; a.W[1]=att_wk; a.W[2]=att_wv; a.W[3]=att_wg;
    a.O[0]=rbuf; a.O[1]=kbuf; a.O[2]=vbuf; a.O[3]=gbuf;
    k_mg<0,0,1,4><<<dim3(CC/128, BTOK/128, 4), 256, 0, stream>>>(a, AA, CC);
  }
  // 4. td path (small; VALU f32)
  k_transpose_f<<<(CC*64 + 255)/256, 256, 0, stream>>>(td_w1, tdw1T, CC, 64);
  k_transpose_f<<<(64*AA + 255)/256, 256, 0, stream>>>(td_w2, tdw2T, 64, AA);
  k_gemm<bf16><<<dim3(1, BTOK/BM), 256, 0, stream>>>(zw, tdw1T, tmp64, nullptr, BTOK, 64, CC, 0);
  k_tanh_f<<<(BTOK*64 + 255)/256, 256, 0, stream>>>(tmp64, tanh64, BTOK*64);
  k_gemm<float><<<dim3(AA/BN, BTOK/BM), 256, 0, stream>>>(tanh64, tdw2T, tdbuf, nullptr, BTOK, AA, 64, 0);
  // 5. chunk-parallel WKV
  k_wprep<<<(BTOK*AA + 255)/256, 256, 0, stream>>>(tdbuf, att_td, wbuf, BTOK*AA);
  k_wkv_chunk<<<32*NCHUNK, 64, 0, stream>>>(kbuf, vbuf, wbuf, chunkS, Ac);
  k_wkv_combine<<<32, 64, 0, stream>>>(chunkS, Ac);
  k_wkv_out<<<32*NCHUNK, 64, 0, stream>>>(rbuf, kbuf, vbuf, wbuf, att_u, chunkS, wkvout);
  // 6. group-norm + silu gate -> ao
  k_gnorm_gate<<<BTOK, 256, 0, stream>>>(wkvout, gbuf, lnx_g, lnx_b, ao);
  // 7. output proj -> attout, split-K=2 atomic (attout zeroed first; wkvout/Ac dead)
  k_zero<<<(BTOK*CC/4 + 255)/256, 256, 0, stream>>>(attout, BTOK*CC/4);
  {
    MGB a{}; a.A[0]=ao; a.W[0]=att_wo; a.O[0]=attout;
    k_mg<1,2,2,1><<<dim3(CC/128, BTOK/128, 2), 256, 0, stream>>>(a, CC, AA);
  }
  // 8. ln2 + ffn mix (ao dead after step 7 -> zero recraw now)
  k_zero<<<(BTOK*CC/4 + 255)/256, 256, 0, stream>>>(recraw, BTOK*CC/4);
  k_ln2mix<<<BTOK, 256, 0, stream>>>(x, attout, ln2_g, ln2_b, fmaa_r, fmaa_k, zfr, zfk);
  // 9. receptance, split-K=2 atomic
  {
    MGB a{}; a.A[0]=zfr; a.W[0]=ffn_wr; a.O[0]=recraw;
    k_mg<0,2,2,1><<<dim3(CC/128, BTOK/128, 2), 256, 0, stream>>>(a, CC, CC);
  }
  // 10. shared expert: key (448 blocks), then value split-K=2 atomic into zeroed val
  {
    MGB a{}; a.A[0]=zfk; a.W[0]=sh_wk; a.O[0]=hk2;
    k_mg<0,1,1,1><<<dim3(IDIM/128, BTOK/128, 1), 256, 0, stream>>>(a, IDIM, CC);
  }
  k_zero<<<(BTOK*CC/4 + 255)/256, 256, 0, stream>>>(val, BTOK*CC/4);
  {
    MGB a{}; a.A[0]=hk2; a.W[0]=sh_wv; a.O[0]=val;
    k_mg<0,2,2,1><<<dim3(CC/128, BTOK/128, 2), 256, 0, stream>>>(a, CC, IDIM);
  }
  // 11. routed experts (key overwrites hk2 after sh_wv consumed it; value atomics into val)
  k_route<<<1, 512, 0, stream>>>(ids, rowmap, counts, offsets);
  k_mg_moe<0,1><<<dim3(BTOK/128, IDIM/128, NEXP), 256, 0, stream>>>(
      (const unsigned short*)zfk, ex_wk, (size_t)IDIM*CC, nullptr, hk2, IDIM, CC,
      rowmap, counts, offsets);
  k_mg_moe<1,2><<<dim3(BTOK/128, CC/128, NEXP*2), 256, 0, stream>>>(
      hk2, ex_wv, (size_t)CC*IDIM, val, nullptr, CC, IDIM,
      rowmap, counts, offsets);
  // 12. final combine -> f32 out
  k_final<<<(BTOK*CC + 255)/256, 256, 0, stream>>>(x, attout, recraw, val, (float*)d_out, BTOK*CC);
}

// Round 5
// 1119.247 us; speedup vs baseline: 1.5936x; 1.4589x over previous
//
#include <hip/hip_runtime.h>
#include <hip/hip_bf16.h>

typedef __hip_bfloat16 bf16;

__device__ __forceinline__ float b2f(bf16 x){ return __bfloat162float(x); }
__device__ __forceinline__ bf16  f2b(float x){ return __float2bfloat16(x); }
__device__ __forceinline__ float ldA(const float* p){ return *p; }
__device__ __forceinline__ float ldA(const bf16* p){ return b2f(*p); }

#define BTOK 2048
#define CC 1024
#define AA 1024
#define IDIM 3584
#define NEXP 8
#define CHUNK 64
#define NCHUNK 16   // 1024 / CHUNK
#define MAXTILE 24  // sum_e ceil(cnt_e/128) <= 2048/128 + 8 = 24

// ---------------- MFMA types / helpers ----------------
typedef __attribute__((ext_vector_type(8))) short   s8v;   // 8 bf16 bit-patterns
typedef __attribute__((ext_vector_type(8))) __bf16  b8v;   // MFMA A/B fragment
typedef __attribute__((ext_vector_type(4))) float   f4v;   // MFMA C/D fragment

__device__ __forceinline__ unsigned short f2bf_bits(float f){   // RNE, matches __float2bfloat16
  unsigned u = __builtin_bit_cast(unsigned, f);
  u += 0x7fffu + ((u >> 16) & 1u);
  return (unsigned short)(u >> 16);
}

// async global->LDS, 16B per lane; dest is wave-uniform base + lane*16 (linear)
#define GLDS16(g, l) __builtin_amdgcn_global_load_lds( \
    (const __attribute__((address_space(1))) void*)(g), \
    (__attribute__((address_space(3)))       void*)(l), 16, 0, 0)

// ---------------- reductions ----------------
__device__ __forceinline__ float block_sum256(float v, float* red){
  #pragma unroll
  for (int o = 32; o > 0; o >>= 1) v += __shfl_down(v, o, 64);
  int lane = threadIdx.x & 63, wid = threadIdx.x >> 6;
  if (lane == 0) red[wid] = v;
  __syncthreads();
  float s = red[0] + red[1] + red[2] + red[3];
  __syncthreads();
  return s;
}

// ---------------- fused pre_ln + ln1 (f32 in, f32 out) ----------------
__global__ __launch_bounds__(256) void k_ln_pre(
    const float* __restrict__ hidden,
    const float* __restrict__ g0, const float* __restrict__ b0,
    const float* __restrict__ g1, const float* __restrict__ b1,
    float* __restrict__ xout, float* __restrict__ hout){
  __shared__ float red[8];
  int t = blockIdx.x, tid = threadIdx.x;
  const float* src = hidden + (size_t)t * CC;
  float v[4];
  #pragma unroll
  for (int i = 0; i < 4; ++i) v[i] = src[tid + 256*i];
  float mean = block_sum256(v[0]+v[1]+v[2]+v[3], red) * (1.f/CC);
  float vs = 0.f;
  #pragma unroll
  for (int i = 0; i < 4; ++i){ float d = v[i]-mean; vs += d*d; }
  float var = block_sum256(vs, red) * (1.f/CC);
  float inv = rsqrtf(var + 1e-5f);
  float xv[4];
  #pragma unroll
  for (int i = 0; i < 4; ++i){
    int c = tid + 256*i;
    xv[i] = (v[i]-mean)*inv*g0[c] + b0[c];
    xout[(size_t)t*CC + c] = xv[i];
  }
  float mean2 = block_sum256(xv[0]+xv[1]+xv[2]+xv[3], red) * (1.f/CC);
  vs = 0.f;
  #pragma unroll
  for (int i = 0; i < 4; ++i){ float d = xv[i]-mean2; vs += d*d; }
  float var2 = block_sum256(vs, red) * (1.f/CC);
  float inv2 = rsqrtf(var2 + 1e-5f);
  #pragma unroll
  for (int i = 0; i < 4; ++i){
    int c = tid + 256*i;
    hout[(size_t)t*CC + c] = (xv[i]-mean2)*inv2*g1[c] + b1[c];
  }
}

// ---------------- token-shift + maa mix -> z_{w,k,v,r,g} (bf16 scratch) ----------------
__global__ __launch_bounds__(256) void k_mix_att(
    const float* __restrict__ h,
    const float* __restrict__ maa_x, const float* __restrict__ w1, const float* __restrict__ w2,
    const float* __restrict__ maa_w, const float* __restrict__ maa_k, const float* __restrict__ maa_v,
    const float* __restrict__ maa_r, const float* __restrict__ maa_g,
    bf16* __restrict__ zw, bf16* __restrict__ zk, bf16* __restrict__ zv,
    bf16* __restrict__ zr, bf16* __restrict__ zg){
  int t = blockIdx.x, tid = threadIdx.x;
  int tb = t & 1023;  // position within batch (T=1024)
  __shared__ float hs[CC], xxs[CC], xxxs[CC], t160[160];
  #pragma unroll
  for (int i = 0; i < 4; ++i){
    int c = tid + 256*i;
    float hv = h[(size_t)t*CC + c];
    float pv = tb ? h[(size_t)(t-1)*CC + c] : 0.f;
    float xx = pv - hv;
    hs[c] = hv; xxs[c] = xx;
    xxxs[c] = hv + xx * maa_x[c];
  }
  __syncthreads();
  if (tid < 160){
    float acc = 0.f;
    for (int c = 0; c < CC; ++c) acc = fmaf(xxxs[c], w1[c*160 + tid], acc);
    t160[tid] = tanhf(acc);
  }
  __syncthreads();
  const float* maas[5] = {maa_w, maa_k, maa_v, maa_r, maa_g};
  bf16* zs[5] = {zw, zk, zv, zr, zg};
  #pragma unroll
  for (int f = 0; f < 5; ++f){
    #pragma unroll
    for (int i = 0; i < 4; ++i){
      int c = tid + 256*i;
      float acc = 0.f;
      #pragma unroll
      for (int d = 0; d < 32; ++d)
        acc = fmaf(t160[f*32 + d], w2[(size_t)(f*32 + d)*CC + c], acc);
      float z = hs[c] + xxs[c] * (maas[f][c] + acc);
      zs[f][(size_t)t*CC + c] = f2b(z);
    }
  }
}

// ---------------- small VALU GEMM (td path): O = A[M,K] @ W[N,K]^T ----------------
// epi 0: store f32   epi 2: atomicAdd f32 (for K-split over blockIdx.z; dest pre-zeroed)
#define BM 64
#define BN 64
#define BK 16
template <typename TA>
__global__ __launch_bounds__(256) void k_gemm(
    const TA* __restrict__ A, const float* __restrict__ W,
    float* __restrict__ Of32, int M, int N, int K, int epi, int kslices){
  __shared__ float As[BK][BM+1];
  __shared__ float Bs[BK][BN+1];
  int bn = blockIdx.x * BN, bm = blockIdx.y * BM;
  int klen = K / kslices;
  int kbeg = blockIdx.z * klen;
  int tid = threadIdx.x;
  int tx = tid & 15, ty = tid >> 4;
  int lr = tid >> 2;
  int lk = (tid & 3) * 4;
  const TA*    Ap = A + (size_t)(bm + lr)*K + lk;
  const float* Wp = W + (size_t)(bn + lr)*K + lk;
  float acc[4][4] = {};
  for (int k0 = kbeg; k0 < kbeg + klen; k0 += BK){
    #pragma unroll
    for (int j = 0; j < 4; ++j){
      As[lk+j][lr] = ldA(Ap + k0 + j);
      Bs[lk+j][lr] = Wp[k0 + j];
    }
    __syncthreads();
    #pragma unroll
    for (int kk = 0; kk < BK; ++kk){
      float av[4], bv[4];
      #pragma unroll
      for (int i = 0; i < 4; ++i) av[i] = As[kk][ty*4 + i];
      #pragma unroll
      for (int j = 0; j < 4; ++j) bv[j] = Bs[kk][tx*4 + j];
      #pragma unroll
      for (int i = 0; i < 4; ++i)
        #pragma unroll
        for (int j = 0; j < 4; ++j) acc[i][j] = fmaf(av[i], bv[j], acc[i][j]);
    }
    __syncthreads();
  }
  #pragma unroll
  for (int i = 0; i < 4; ++i){
    int row = bm + ty*4 + i;
    #pragma unroll
    for (int j = 0; j < 4; ++j){
      int col = bn + tx*4 + j;
      size_t oi = (size_t)row*N + col;
      if (epi == 0) Of32[oi] = acc[i][j];
      else          atomicAdd(Of32 + oi, acc[i][j]);
    }
  }
}

// ================= m97-style MFMA GEMM: O[M,N] = A[M,K] @ W[N,K]^T =================
// 128x128x32 tile, 4 waves (2x2), wave = 64x64 = 4x4 frags of 16x16x32 bf16.
// Staging via global_load_lds width-16. A: bf16 LDS [128][32] linear. W: f32 LDS with
// XOR-source-swizzle chunk^=(row&7); read applies same XOR; f32->bf16 at frag read.
struct MGB { const void* A[4]; const float* W[4]; void* O[4]; };

template<int AF32, int EPI, int SPLITK, int NB>   // EPI: 0 store f32, 1 relu^2->bf16, 2 atomicAdd f32
__global__ __launch_bounds__(256) void k_mg(MGB args, int N, int K){
  constexpr int ABYTES = AF32 ? 16384 : 8192;
  __shared__ char lds[ABYTES + 16384];
  unsigned short* As  = (unsigned short*)lds;     // bf16 [128][32] linear
  float*          AsF = (float*)lds;              // f32  [128][32] swizzled
  float*          BsF = (float*)(lds + ABYTES);   // f32  [128][32] swizzled

  const int bz = blockIdx.z;
  const int bi = bz / SPLITK, kh = bz % SPLITK;
  const int Kh = K / SPLITK, kbeg = kh * Kh;
  const unsigned short* Ab = (const unsigned short*)args.A[bi];
  const float*          Af = (const float*)args.A[bi];
  const float*          W  = args.W[bi];
  const int bm = blockIdx.y*128, bn = blockIdx.x*128;
  const int tid = threadIdx.x, l = tid & 63, w = tid >> 6;
  const int mr = (w >> 1)*64, nc = (w & 1)*64;
  const int r4 = tid >> 2, c4 = tid & 3;
  const int r8 = tid >> 3, c8 = tid & 7;

  f4v acc[4][4];
  #pragma unroll
  for (int i = 0; i < 4; ++i)
    #pragma unroll
    for (int j = 0; j < 4; ++j){ f4v z = {0.f,0.f,0.f,0.f}; acc[i][j] = z; }

  const int nk = Kh / 32;
  for (int kt = 0; kt < nk; ++kt){
    const int kk = kbeg + kt*32;
    __syncthreads();
    if (!AF32){
      GLDS16(Ab + (size_t)(bm + r4      )*K + kk + c4*8, (char*)As + tid*16);
      GLDS16(Ab + (size_t)(bm + 64 + r4 )*K + kk + c4*8, (char*)As + 4096 + tid*16);
    } else {
      #pragma unroll
      for (int s = 0; s < 4; ++s){
        int r = s*32 + r8, cs = c8 ^ (r & 7);
        GLDS16(Af + (size_t)(bm + r)*K + kk + cs*4, (char*)AsF + s*4096 + tid*16);
      }
    }
    #pragma unroll
    for (int s = 0; s < 4; ++s){
      int r = s*32 + r8, cs = c8 ^ (r & 7);
      GLDS16(W + (size_t)(bn + r)*K + kk + cs*4, (char*)BsF + s*4096 + tid*16);
    }
    __syncthreads();
    b8v afr[4], bfr[4];
    #pragma unroll
    for (int f = 0; f < 4; ++f){
      if (!AF32){
        afr[f] = *(const b8v*)&As[(mr + f*16 + (l&15))*32 + (l>>4)*8];
      } else {
        int row = mr + f*16 + (l&15), s = row & 7, p = (2*(l>>4)) ^ s;
        f4v q0 = *(const f4v*)&AsF[row*32 + p*4];
        f4v q1 = *(const f4v*)&AsF[row*32 + (p^1)*4];
        s8v t;
        #pragma unroll
        for (int j = 0; j < 4; ++j){ t[j] = (short)f2bf_bits(q0[j]); t[4+j] = (short)f2bf_bits(q1[j]); }
        afr[f] = __builtin_bit_cast(b8v, t);
      }
      {
        int row = nc + f*16 + (l&15), s = row & 7, p = (2*(l>>4)) ^ s;
        f4v q0 = *(const f4v*)&BsF[row*32 + p*4];
        f4v q1 = *(const f4v*)&BsF[row*32 + (p^1)*4];
        s8v t;
        #pragma unroll
        for (int j = 0; j < 4; ++j){ t[j] = (short)f2bf_bits(q0[j]); t[4+j] = (short)f2bf_bits(q1[j]); }
        bfr[f] = __builtin_bit_cast(b8v, t);
      }
    }
    #pragma unroll
    for (int fr = 0; fr < 4; ++fr)
      #pragma unroll
      for (int fc = 0; fc < 4; ++fc)
        acc[fr][fc] = __builtin_amdgcn_mfma_f32_16x16x32_bf16(afr[fr], bfr[fc], acc[fr][fc], 0, 0, 0);
  }
  const int rb = bm + mr + ((l >> 4) << 2);
  const int cb = bn + nc + (l & 15);
  #pragma unroll
  for (int fr = 0; fr < 4; ++fr)
    #pragma unroll
    for (int fc = 0; fc < 4; ++fc)
      #pragma unroll
      for (int j = 0; j < 4; ++j){
        size_t oi = (size_t)(rb + fr*16 + j)*N + (cb + fc*16);
        float v = acc[fr][fc][j];
        if (EPI == 0)      ((float*)args.O[bi])[oi] = v;
        else if (EPI == 1){ v = v > 0.f ? v : 0.f; ((unsigned short*)args.O[bi])[oi] = f2bf_bits(v*v); }
        else               atomicAdd((float*)args.O[bi] + oi, v);
      }
}

// ---------------- MoE MFMA GEMM, worklist-driven (no periodic dead blocks) ----------------
// grid = (MAXTILE, N/128, SPLITK); tilemap[ti] = (expert<<8)|row_tile, built by k_route.
// Dead blocks (ti >= ntiles) are contiguous at the tail -> full CU spread for live ones.
// MODE 0 (key): A rows gathered via rowmap, out compact rows, relu^2 -> bf16
// MODE 1 (value): A rows compact, out scattered via rowmap, atomicAdd f32
template<int MODE>
__global__ __launch_bounds__(256) void k_mg_moe(
    const unsigned short* __restrict__ A, const float* __restrict__ Wbase, size_t wstride,
    float* __restrict__ Of32, unsigned short* __restrict__ Obf, int N, int K, int splitk,
    const int* __restrict__ rowmap, const int* __restrict__ counts,
    const int* __restrict__ offsets, const int* __restrict__ tilemap,
    const int* __restrict__ ntilesp){
  const int ti = blockIdx.x;
  if (ti >= *ntilesp) return;
  const int tmv = tilemap[ti];
  const int e = tmv >> 8;
  const int mbase = (tmv & 255) * 128;
  const int cnt = counts[e];
  const int obase = offsets[e];
  const float* W = Wbase + (size_t)e*wstride;
  const int kh = blockIdx.z;
  const int Kh = K / splitk, kbeg = kh * Kh;
  __shared__ char lds[8192 + 16384];
  unsigned short* As  = (unsigned short*)lds;
  float*          BsF = (float*)(lds + 8192);
  const int tid = threadIdx.x, l = tid & 63, w = tid >> 6;
  const int bn = blockIdx.y*128;
  const int mr = (w >> 1)*64, nc = (w & 1)*64;
  const int r4 = tid >> 2, c4 = tid & 3;
  const int r8 = tid >> 3, c8 = tid & 7;

  int grow[2];
  #pragma unroll
  for (int s = 0; s < 2; ++s){
    int lr = mbase + s*64 + r4;
    lr = lr < cnt ? lr : cnt - 1;                 // clamp: garbage rows masked at epilogue
    grow[s] = (MODE == 0) ? rowmap[obase + lr] : (obase + lr);
  }

  f4v acc[4][4];
  #pragma unroll
  for (int i = 0; i < 4; ++i)
    #pragma unroll
    for (int j = 0; j < 4; ++j){ f4v z = {0.f,0.f,0.f,0.f}; acc[i][j] = z; }

  const int nk = Kh / 32;
  for (int kt = 0; kt < nk; ++kt){
    const int kk = kbeg + kt*32;
    __syncthreads();
    GLDS16(A + (size_t)grow[0]*K + kk + c4*8, (char*)As + tid*16);
    GLDS16(A + (size_t)grow[1]*K + kk + c4*8, (char*)As + 4096 + tid*16);
    #pragma unroll
    for (int s = 0; s < 4; ++s){
      int r = s*32 + r8, cs = c8 ^ (r & 7);
      GLDS16(W + (size_t)(bn + r)*K + kk + cs*4, (char*)BsF + s*4096 + tid*16);
    }
    __syncthreads();
    b8v afr[4], bfr[4];
    #pragma unroll
    for (int f = 0; f < 4; ++f){
      afr[f] = *(const b8v*)&As[(mr + f*16 + (l&15))*32 + (l>>4)*8];
      int row = nc + f*16 + (l&15), s = row & 7, p = (2*(l>>4)) ^ s;
      f4v q0 = *(const f4v*)&BsF[row*32 + p*4];
      f4v q1 = *(const f4v*)&BsF[row*32 + (p^1)*4];
      s8v t;
      #pragma unroll
      for (int j = 0; j < 4; ++j){ t[j] = (short)f2bf_bits(q0[j]); t[4+j] = (short)f2bf_bits(q1[j]); }
      bfr[f] = __builtin_bit_cast(b8v, t);
    }
    #pragma unroll
    for (int fr = 0; fr < 4; ++fr)
      #pragma unroll
      for (int fc = 0; fc < 4; ++fc)
        acc[fr][fc] = __builtin_amdgcn_mfma_f32_16x16x32_bf16(afr[fr], bfr[fc], acc[fr][fc], 0, 0, 0);
  }
  const int rb = mbase + mr + ((l >> 4) << 2);
  const int cb = bn + nc + (l & 15);
  #pragma unroll
  for (int fr = 0; fr < 4; ++fr)
    #pragma unroll
    for (int fc = 0; fc < 4; ++fc)
      #pragma unroll
      for (int j = 0; j < 4; ++j){
        int lrow = rb + fr*16 + j;
        if (lrow >= cnt) continue;
        int col = cb + fc*16;
        float v = acc[fr][fc][j];
        if (MODE == 0){
          size_t oi = (size_t)(obase + lrow)*N + col;
          v = v > 0.f ? v : 0.f;
          Obf[oi] = f2bf_bits(v*v);
        } else {
          int orow = rowmap[obase + lrow];
          atomicAdd(Of32 + (size_t)orow*N + col, v);
        }
      }
}

// ================= chunk-parallel WKV =================
__global__ void k_wprep(const float* __restrict__ td, const float* __restrict__ bias,
                        float* __restrict__ wbuf, int n){
  int i = blockIdx.x*256 + threadIdx.x;
  if (i >= n) return;
  wbuf[i] = expf(-expf(td[i] + bias[i & (AA-1)]));
}

__global__ __launch_bounds__(64) void k_wkv_chunk(
    const float* __restrict__ kb, const float* __restrict__ vb,
    const float* __restrict__ wb, float* __restrict__ Bc, float* __restrict__ Ac){
  int blk = blockIdx.x;
  int stream = blk >> 4, c = blk & (NCHUNK-1);
  int b = stream >> 4, hh = stream & 15;
  int lane = threadIdx.x;
  __shared__ float ks[64], ws[64];
  float s[64];
  #pragma unroll
  for (int n = 0; n < 64; ++n) s[n] = 0.f;
  float prod = 1.f;
  int t0 = c * CHUNK;
  for (int tt = 0; tt < CHUNK; ++tt){
    size_t idx = ((size_t)(b*1024 + t0 + tt))*AA + hh*64 + lane;
    float kt = kb[idx], vt = vb[idx], wt = wb[idx];
    __syncthreads();
    ks[lane] = kt; ws[lane] = wt;
    __syncthreads();
    prod *= wt;
    #pragma unroll
    for (int n = 0; n < 64; ++n)
      s[n] = fmaf(ws[n], s[n], ks[n]*vt);
  }
  float* Bp = Bc + ((size_t)stream*NCHUNK + c)*4096;
  #pragma unroll
  for (int n = 0; n < 64; ++n) Bp[n*64 + lane] = s[n];
  Ac[((size_t)stream*NCHUNK + c)*64 + lane] = prod;
}

__global__ __launch_bounds__(64) void k_wkv_combine(
    float* __restrict__ Bc, const float* __restrict__ Ac){
  int stream = blockIdx.x;
  int lane = threadIdx.x;
  __shared__ float as[64];
  float S[64];
  #pragma unroll
  for (int n = 0; n < 64; ++n) S[n] = 0.f;
  for (int c = 0; c < NCHUNK; ++c){
    __syncthreads();
    as[lane] = Ac[((size_t)stream*NCHUNK + c)*64 + lane];
    __syncthreads();
    float* Bp = Bc + ((size_t)stream*NCHUNK + c)*4096;
    #pragma unroll
    for (int n = 0; n < 64; ++n){
      float bcv = Bp[n*64 + lane];
      Bp[n*64 + lane] = S[n];
      S[n] = fmaf(as[n], S[n], bcv);
    }
  }
}

__global__ __launch_bounds__(64) void k_wkv_out(
    const float* __restrict__ rb, const float* __restrict__ kb,
    const float* __restrict__ vb, const float* __restrict__ wb,
    const float* __restrict__ u, const float* __restrict__ Sc,
    float* __restrict__ ob){
  int blk = blockIdx.x;
  int stream = blk >> 4, c = blk & (NCHUNK-1);
  int b = stream >> 4, hh = stream & 15;
  int lane = threadIdx.x;
  __shared__ float rs[64], ks[64], ws[64], us[64];
  us[lane] = u[hh*64 + lane];
  const float* Sp = Sc + ((size_t)stream*NCHUNK + c)*4096;
  float s[64];
  #pragma unroll
  for (int n = 0; n < 64; ++n) s[n] = Sp[n*64 + lane];
  int t0 = c * CHUNK;
  for (int tt = 0; tt < CHUNK; ++tt){
    size_t idx = ((size_t)(b*1024 + t0 + tt))*AA + hh*64 + lane;
    float rt = rb[idx], kt = kb[idx], vt = vb[idx], wt = wb[idx];
    __syncthreads();
    rs[lane] = rt; ks[lane] = kt; ws[lane] = wt;
    __syncthreads();
    float o0 = 0.f, o1 = 0.f;
    #pragma unroll
    for (int n = 0; n < 64; n += 2){
      float kv0 = ks[n]*vt;
      o0 = fmaf(rs[n], fmaf(us[n], kv0, s[n]), o0);
      s[n] = fmaf(ws[n], s[n], kv0);
      float kv1 = ks[n+1]*vt;
      o1 = fmaf(rs[n+1], fmaf(us[n+1], kv1, s[n+1]), o1);
      s[n+1] = fmaf(ws[n+1], s[n+1], kv1);
    }
    ob[idx] = o0 + o1;
  }
}

// ---------------- group-norm over heads + silu(g) gate -> ao (f32) ----------------
__global__ __launch_bounds__(256) void k_gnorm_gate(
    const float* __restrict__ ob, const float* __restrict__ gb,
    const float* __restrict__ lg, const float* __restrict__ lb, float* __restrict__ ao){
  int t = blockIdx.x, tid = threadIdx.x;
  int lane = tid & 63, wid = tid >> 6;
  #pragma unroll
  for (int i = 0; i < 4; ++i){
    int head = wid*4 + i;
    int cidx = head*64 + lane;
    size_t idx = (size_t)t*AA + cidx;
    float v = ob[idx];
    float s1 = v, s2 = v*v;
    #pragma unroll
    for (int o = 32; o > 0; o >>= 1){
      s1 += __shfl_xor(s1, o, 64);
      s2 += __shfl_xor(s2, o, 64);
    }
    float m   = s1 * (1.f/64.f);
    float var = s2 * (1.f/64.f) - m*m;
    float nv  = (v - m) * rsqrtf(var + 6.4e-4f) * lg[cidx] + lb[cidx];
    float gv  = gb[idx];
    float gate = gv / (1.f + expf(-gv));
    ao[idx] = nv * gate;
  }
}

// ---------------- ln2 + ffn token-shift mix -> zfr,zfk ----------------
__global__ __launch_bounds__(256) void k_ln2mix(
    const float* __restrict__ xr, const float* __restrict__ at,
    const float* __restrict__ g2, const float* __restrict__ b2v,
    const float* __restrict__ fmaa_r, const float* __restrict__ fmaa_k,
    bf16* __restrict__ zfr, bf16* __restrict__ zfk){
  __shared__ float red[8];
  int t = blockIdx.x, tid = threadIdx.x;
  int tb = t & 1023;
  float cur[4], prv[4];
  #pragma unroll
  for (int i = 0; i < 4; ++i){
    int c = tid + 256*i;
    cur[i] = xr[(size_t)t*CC + c] + at[(size_t)t*CC + c];
    prv[i] = tb ? (xr[(size_t)(t-1)*CC + c] + at[(size_t)(t-1)*CC + c]) : 0.f;
  }
  float m1 = block_sum256(cur[0]+cur[1]+cur[2]+cur[3], red) * (1.f/CC);
  float vs = 0.f;
  #pragma unroll
  for (int i = 0; i < 4; ++i){ float d = cur[i]-m1; vs += d*d; }
  float inv1 = rsqrtf(block_sum256(vs, red)*(1.f/CC) + 1e-5f);
  float m2 = block_sum256(prv[0]+prv[1]+prv[2]+prv[3], red) * (1.f/CC);
  vs = 0.f;
  #pragma unroll
  for (int i = 0; i < 4; ++i){ float d = prv[i]-m2; vs += d*d; }
  float inv2 = rsqrtf(block_sum256(vs, red)*(1.f/CC) + 1e-5f);
  #pragma unroll
  for (int i = 0; i < 4; ++i){
    int c = tid + 256*i;
    float hc = (cur[i]-m1)*inv1*g2[c] + b2v[c];
    float hp = tb ? ((prv[i]-m2)*inv2*g2[c] + b2v[c]) : 0.f;
    float d = hp - hc;
    zfr[(size_t)t*CC + c] = f2b(hc + d * fmaa_r[c]);
    zfk[(size_t)t*CC + c] = f2b(hc + d * fmaa_k[c]);
  }
}

// ---------------- expert routing + worklist build (deterministic) ----------------
__global__ __launch_bounds__(512) void k_route(
    const int* __restrict__ ids, int* __restrict__ rowmap,
    int* __restrict__ counts, int* __restrict__ offsets,
    int* __restrict__ tilemap, int* __restrict__ ntilesp){
  int wid = threadIdx.x >> 6, lane = threadIdx.x & 63;
  int e = wid;
  __shared__ int cnt_s[8];
  int c = 0;
  for (int t0 = 0; t0 < BTOK; t0 += 64){
    int a = (ids[t0 + lane] * 5099) & 7;
    unsigned long long m = __ballot(a == e);
    c += __popcll(m);
  }
  if (lane == 0) cnt_s[e] = c;
  __syncthreads();
  int off = 0;
  for (int i = 0; i < e; ++i) off += cnt_s[i];
  if (lane == 0){ counts[e] = cnt_s[e]; offsets[e] = off; }
  if (threadIdx.x == 0){
    int nt = 0;
    for (int ee = 0; ee < 8; ++ee){
      int nct = (cnt_s[ee] + 127) >> 7;
      for (int xt = 0; xt < nct; ++xt) tilemap[nt++] = (ee << 8) | xt;
    }
    *ntilesp = nt;
  }
  int pos = off;
  for (int t0 = 0; t0 < BTOK; t0 += 64){
    int t = t0 + lane;
    int a = (ids[t] * 5099) & 7;
    unsigned long long m = __ballot(a == e);
    if (a == e){
      int r = __popcll(m & ((1ull << lane) - 1ull));
      rowmap[pos + r] = t;
    }
    pos += __popcll(m);
  }
}

// ---------------- small elementwise ----------------
__global__ void k_tanh_f(const float* __restrict__ in, float* __restrict__ out, int n){
  int i = blockIdx.x*256 + threadIdx.x;
  if (i >= n) return;
  out[i] = tanhf(in[i]);
}
__global__ void k_transpose_f(const float* __restrict__ in, float* __restrict__ out, int R, int Ccol){
  int idx = blockIdx.x*256 + threadIdx.x;
  if (idx >= R*Ccol) return;
  int r = idx / Ccol, c = idx % Ccol;
  out[c*R + r] = in[idx];
}
__global__ void k_zero(float* __restrict__ p, int n4){
  int i = blockIdx.x*256 + threadIdx.x;
  if (i >= n4) return;
  f4v z = {0.f,0.f,0.f,0.f};
  ((f4v*)p)[i] = z;
}
__global__ void k_final(const float* __restrict__ xr, const float* __restrict__ at,
                        const float* __restrict__ rr, const float* __restrict__ val,
                        float* __restrict__ out, int n){
  int i = blockIdx.x*256 + threadIdx.x;
  if (i >= n) return;
  float r = 1.f / (1.f + expf(-rr[i]));
  out[i] = xr[i] + at[i] + r*val[i];
}

// ---------------- launch ----------------
extern "C" void kernel_launch(void* const* d_in, const int* in_sizes, int n_in,
                              void* d_out, int out_size, void* d_ws, size_t ws_size,
                              hipStream_t stream) {
  const float* hidden  = (const float*)d_in[0];
  const int*   ids     = (const int*)  d_in[1];
  const float* pre_g   = (const float*)d_in[2];
  const float* pre_b   = (const float*)d_in[3];
  const float* ln1_g   = (const float*)d_in[4];
  const float* ln1_b   = (const float*)d_in[5];
  const float* ln2_g   = (const float*)d_in[6];
  const float* ln2_b   = (const float*)d_in[7];
  const float* maa_x   = (const float*)d_in[8];
  const float* maa_w   = (const float*)d_in[9];
  const float* maa_k   = (const float*)d_in[10];
  const float* maa_v   = (const float*)d_in[11];
  const float* maa_r   = (const float*)d_in[12];
  const float* maa_g   = (const float*)d_in[13];
  const float* maa_w1  = (const float*)d_in[14];
  const float* maa_w2  = (const float*)d_in[15];
  const float* att_td  = (const float*)d_in[16];
  const float* td_w1   = (const float*)d_in[17];
  const float* td_w2   = (const float*)d_in[18];
  const float* att_u   = (const float*)d_in[19];
  const float* att_wr  = (const float*)d_in[20];
  const float* att_wk  = (const float*)d_in[21];
  const float* att_wv  = (const float*)d_in[22];
  const float* att_wg  = (const float*)d_in[23];
  const float* att_wo  = (const float*)d_in[24];
  const float* lnx_g   = (const float*)d_in[25];
  const float* lnx_b   = (const float*)d_in[26];
  const float* fmaa_k  = (const float*)d_in[27];
  const float* fmaa_r  = (const float*)d_in[28];
  const float* ffn_wr  = (const float*)d_in[29];
  const float* sh_wk   = (const float*)d_in[30];
  const float* sh_wv   = (const float*)d_in[31];
  const float* ex_wk   = (const float*)d_in[32];
  const float* ex_wv   = (const float*)d_in[33];
  (void)ws_size; (void)n_in; (void)in_sizes; (void)out_size;

  // ---- workspace layout: 8 x 8 MiB planes, total EXACTLY 64 MiB (unchanged) ----
  char* base = (char*)d_ws;
  const size_t MiB = 1024ull*1024ull;
  float* x      = (float*)(base + 0*MiB);
  float* h      = (float*)(base + 8*MiB);
  float* rbuf   = h;
  float* kbuf   = (float*)(base + 16*MiB);
  float* vbuf   = (float*)(base + 24*MiB);
  unsigned short* hk2 = (unsigned short*)(base + 16*MiB);  // 16..30 MiB
  int*   rowmap = (int*)(base + 31*MiB);     // in P3 tail hole; vbuf dead by route time
  int*   counts = rowmap + BTOK;
  int*   offsets= counts + 64;
  int*   tilemap= offsets + 64;
  int*   ntilesp= tilemap + 64;
  float* gbuf   = (float*)(base + 32*MiB);
  float* val    = gbuf;
  bf16*  zw     = (bf16*)(base + 40*MiB);
  bf16*  zk     = (bf16*)(base + 44*MiB);
  float* tdbuf  = (float*)(base + 40*MiB);
  float* Ac     = (float*)(base + 40*MiB);
  float* wkvout = (float*)(base + 40*MiB);
  float* attout = (float*)(base + 40*MiB);
  bf16*  zr     = (bf16*)(base + 48*MiB);
  bf16*  zg     = (bf16*)(base + 52*MiB);
  float* wbuf   = (float*)(base + 48*MiB);
  float* ao     = (float*)(base + 48*MiB);
  float* recraw = (float*)(base + 48*MiB);
  bf16*  zv     = (bf16*)(base + 56*MiB);
  float* tdw1T  = (float*)(base + 60*MiB);
  float* tdw2T  = (float*)(base + 60*MiB + 256*1024);
  float* tmp64  = (float*)(base + 60*MiB + 512*1024);
  float* tanh64 = (float*)(base + 61*MiB);
  float* chunkS = (float*)(base + 56*MiB);
  bf16*  zfr    = (bf16*)(base + 56*MiB);
  bf16*  zfk    = (bf16*)(base + 60*MiB);

  // 1. pre_ln + ln1
  k_ln_pre<<<BTOK, 256, 0, stream>>>(hidden, pre_g, pre_b, ln1_g, ln1_b, x, h);
  // 2. attention maa mix
  k_mix_att<<<BTOK, 256, 0, stream>>>(h, maa_x, maa_w1, maa_w2,
                                      maa_w, maa_k, maa_v, maa_r, maa_g,
                                      zw, zk, zv, zr, zg);
  // 3. r,k,v,g projections: ONE z-batched dispatch, 512 blocks
  {
    MGB a{};
    a.A[0]=zr; a.A[1]=zk; a.A[2]=zv; a.A[3]=zg;
    a.W[0]=att_wr; a.W[1]=att_wk; a.W[2]=att_wv; a.W[3]=att_wg;
    a.O[0]=rbuf; a.O[1]=kbuf; a.O[2]=vbuf; a.O[3]=gbuf;
    k_mg<0,0,1,4><<<dim3(CC/128, BTOK/128, 4), 256, 0, stream>>>(a, AA, CC);
  }
  // 4. td path; first GEMM K-split 8 ways (was 32-block starved)
  k_transpose_f<<<(CC*64 + 255)/256, 256, 0, stream>>>(td_w1, tdw1T, CC, 64);
  k_transpose_f<<<(64*AA + 255)/256, 256, 0, stream>>>(td_w2, tdw2T, 64, AA);
  k_zero<<<(BTOK*64/4 + 255)/256, 256, 0, stream>>>(tmp64, BTOK*64/4);
  k_gemm<bf16><<<dim3(1, BTOK/BM, 8), 256, 0, stream>>>(zw, tdw1T, tmp64, BTOK, 64, CC, 2, 8);
  k_tanh_f<<<(BTOK*64 + 255)/256, 256, 0, stream>>>(tmp64, tanh64, BTOK*64);
  k_gemm<float><<<dim3(AA/BN, BTOK/BM, 1), 256, 0, stream>>>(tanh64, tdw2T, tdbuf, BTOK, AA, 64, 0, 1);
  // 5. chunk-parallel WKV
  k_wprep<<<(BTOK*AA + 255)/256, 256, 0, stream>>>(tdbuf, att_td, wbuf, BTOK*AA);
  k_wkv_chunk<<<32*NCHUNK, 64, 0, stream>>>(kbuf, vbuf, wbuf, chunkS, Ac);
  k_wkv_combine<<<32, 64, 0, stream>>>(chunkS, Ac);
  k_wkv_out<<<32*NCHUNK, 64, 0, stream>>>(rbuf, kbuf, vbuf, wbuf, att_u, chunkS, wkvout);
  // 6. group-norm + silu gate -> ao
  k_gnorm_gate<<<BTOK, 256, 0, stream>>>(wkvout, gbuf, lnx_g, lnx_b, ao);
  // 7. output proj -> attout, split-K=2 atomic (attout zeroed; wkvout dead)
  k_zero<<<(BTOK*CC/4 + 255)/256, 256, 0, stream>>>(attout, BTOK*CC/4);
  {
    MGB a{}; a.A[0]=ao; a.W[0]=att_wo; a.O[0]=attout;
    k_mg<1,2,2,1><<<dim3(CC/128, BTOK/128, 2), 256, 0, stream>>>(a, CC, AA);
  }
  // 8. ln2 + ffn mix
  k_zero<<<(BTOK*CC/4 + 255)/256, 256, 0, stream>>>(recraw, BTOK*CC/4);
  k_ln2mix<<<BTOK, 256, 0, stream>>>(x, attout, ln2_g, ln2_b, fmaa_r, fmaa_k, zfr, zfk);
  // 9. receptance, split-K=2 atomic
  {
    MGB a{}; a.A[0]=zfr; a.W[0]=ffn_wr; a.O[0]=recraw;
    k_mg<0,2,2,1><<<dim3(CC/128, BTOK/128, 2), 256, 0, stream>>>(a, CC, CC);
  }
  // 10. shared expert: key, then value split-K=2 atomic into zeroed val
  {
    MGB a{}; a.A[0]=zfk; a.W[0]=sh_wk; a.O[0]=hk2;
    k_mg<0,1,1,1><<<dim3(IDIM/128, BTOK/128, 1), 256, 0, stream>>>(a, IDIM, CC);
  }
  k_zero<<<(BTOK*CC/4 + 255)/256, 256, 0, stream>>>(val, BTOK*CC/4);
  {
    MGB a{}; a.A[0]=hk2; a.W[0]=sh_wv; a.O[0]=val;
    k_mg<0,2,2,1><<<dim3(CC/128, BTOK/128, 2), 256, 0, stream>>>(a, CC, IDIM);
  }
  // 11. routed experts via worklist (dense active blocks, no periodic holes)
  k_route<<<1, 512, 0, stream>>>(ids, rowmap, counts, offsets, tilemap, ntilesp);
  k_mg_moe<0><<<dim3(MAXTILE, IDIM/128, 1), 256, 0, stream>>>(
      (const unsigned short*)zfk, ex_wk, (size_t)IDIM*CC, nullptr, hk2, IDIM, CC, 1,
      rowmap, counts, offsets, tilemap, ntilesp);
  k_mg_moe<1><<<dim3(MAXTILE, CC/128, 2), 256, 0, stream>>>(
      hk2, ex_wv, (size_t)CC*IDIM, val, nullptr, CC, IDIM, 2,
      rowmap, counts, offsets, tilemap, ntilesp);
  // 12. final combine -> f32 out
  k_final<<<(BTOK*CC + 255)/256, 256, 0, stream>>>(x, attout, recraw, val, (float*)d_out, BTOK*CC);
}